// Round 2
// baseline (808.858 us; speedup 1.0000x reference)
//
#include <hip/hip_runtime.h>
#include <cstdint>

#define DEV __device__ __forceinline__

typedef __attribute__((ext_vector_type(8))) short bf16x8;
typedef __attribute__((ext_vector_type(4))) float f32x4;

#define MFMA(a,b,c) __builtin_amdgcn_mfma_f32_16x16x32_bf16((a),(b),(c),0,0,0)

DEV unsigned short f2bf(float f) {
  union { float f; unsigned u; } v; v.f = f;
  unsigned r = v.u + 0x7fffu + ((v.u >> 16) & 1u);
  return (unsigned short)(r >> 16);
}
DEV float bf2f(unsigned short s) {
  union { unsigned u; float f; } v; v.u = ((unsigned)s) << 16; return v.f;
}

// ---------------- prep kernels ----------------

// Wqkv_t[c3][d] = sum_r U[h][d][r]*V[h][r][k],  c3 = proj*1024 + h*64 + k
__global__ void k_build_wqkv(const float* __restrict__ Uq, const float* __restrict__ Vq,
                             const float* __restrict__ Uk, const float* __restrict__ Vk,
                             const float* __restrict__ Uv, const float* __restrict__ Vv,
                             unsigned short* __restrict__ W) {
  int idx = blockIdx.x * 256 + threadIdx.x;       // [0, 3072*1024)
  int d = idx & 1023;
  int c3 = idx >> 10;
  int proj = c3 >> 10;
  int c = c3 & 1023;
  int h = c >> 6, k = c & 63;
  const float* U = (proj == 0) ? Uq : (proj == 1) ? Uk : Uv;
  const float* V = (proj == 0) ? Vq : (proj == 1) ? Vk : Vv;
  const float* Urow = U + ((size_t)h * 1024 + d) * 32;
  const float* Vcol = V + (size_t)h * 32 * 64 + k;
  float s = 0.f;
#pragma unroll
  for (int r = 0; r < 32; ++r) s += Urow[r] * Vcol[r * 64];
  W[(size_t)c3 * 1024 + d] = f2bf(s);
}

__global__ void k_concat_bias(const float* __restrict__ bq, const float* __restrict__ bk,
                              const float* __restrict__ bv, float* __restrict__ out) {
  int i = blockIdx.x * 256 + threadIdx.x;
  if (i < 1024) out[i] = bq[i];
  else if (i < 2048) out[i] = bk[i - 1024];
  else if (i < 3072) out[i] = bv[i - 2048];
}

__global__ void k_f2bf(const float* __restrict__ in, unsigned short* __restrict__ out, int n) {
  int i = blockIdx.x * 256 + threadIdx.x;
  if (i < n) out[i] = f2bf(in[i]);
}

// fp32 [R][C] -> bf16 [C][R]
__global__ void k_transpose_bf16(const float* __restrict__ in, unsigned short* __restrict__ out,
                                 int R, int C) {
  __shared__ float tile[32][33];
  int c0 = blockIdx.x * 32, r0 = blockIdx.y * 32;
  int tx = threadIdx.x, ty = threadIdx.y;
#pragma unroll
  for (int i = ty; i < 32; i += 8)
    tile[i][tx] = in[(size_t)(r0 + i) * C + c0 + tx];
  __syncthreads();
#pragma unroll
  for (int i = ty; i < 32; i += 8)
    out[(size_t)(c0 + i) * R + r0 + tx] = f2bf(tile[tx][i]);
}

// ---------------- layernorm (row = 1024 fp32 -> bf16) ----------------
__global__ __launch_bounds__(256) void k_layernorm(const float* __restrict__ x,
                                                   const float* __restrict__ w,
                                                   const float* __restrict__ b,
                                                   unsigned short* __restrict__ out) {
  int row = blockIdx.x;
  int tid = threadIdx.x;
  int lane = tid & 63, wid = tid >> 6;
  const float4 v = ((const float4*)(x + (size_t)row * 1024))[tid];
  float s = v.x + v.y + v.z + v.w;
  float s2 = v.x * v.x + v.y * v.y + v.z * v.z + v.w * v.w;
#pragma unroll
  for (int o = 1; o < 64; o <<= 1) { s += __shfl_xor(s, o); s2 += __shfl_xor(s2, o); }
  __shared__ float as_[4], as2_[4];
  if (lane == 0) { as_[wid] = s; as2_[wid] = s2; }
  __syncthreads();
  s = as_[0] + as_[1] + as_[2] + as_[3];
  s2 = as2_[0] + as2_[1] + as2_[2] + as2_[3];
  float mean = s * (1.f / 1024.f);
  float var = s2 * (1.f / 1024.f) - mean * mean;
  float inv = rsqrtf(var + 1e-5f);
  const float4 wv = ((const float4*)w)[tid];
  const float4 bv = ((const float4*)b)[tid];
  union { unsigned short u[4]; unsigned long long ll; } o;
  o.u[0] = f2bf((v.x - mean) * inv * wv.x + bv.x);
  o.u[1] = f2bf((v.y - mean) * inv * wv.y + bv.y);
  o.u[2] = f2bf((v.z - mean) * inv * wv.z + bv.z);
  o.u[3] = f2bf((v.w - mean) * inv * wv.w + bv.w);
  ((unsigned long long*)(out + (size_t)row * 1024))[tid] = o.ll;
}

// ---------------- GEMM: C[8192 x N] = A[8192 x K](bf16) * Bt[N x K]^T ----------------
// EPI 0: bf16 out;  1: bf16 out + bias;  2: f32 out + bias + resid
#define LDT 56

template <int EPI>
__global__ __launch_bounds__(256, 2) void k_gemm(const unsigned short* __restrict__ A,
                                                 const unsigned short* __restrict__ Bt,
                                                 const float* __restrict__ bias,
                                                 const float* __restrict__ resid,
                                                 void* __restrict__ outp, int N, int K) {
  __shared__ short Al[128 * LDT];
  __shared__ short Bl[128 * LDT];
  int tid = threadIdx.x, lane = tid & 63, wid = tid >> 6;
  int wr = wid >> 1, wc = wid & 1;
  size_t row0 = (size_t)blockIdx.y * 128;
  int col0 = blockIdx.x * 128;
  int srow = tid >> 1, scol = (tid & 1) << 4;
  const unsigned short* Ap = A + (row0 + srow) * K + scol;
  const unsigned short* Bp = Bt + (size_t)(col0 + srow) * K + scol;
  f32x4 acc[4][4] = {};
  int fr = lane & 15, fk = (lane >> 4) << 3;
  for (int k0 = 0; k0 < K; k0 += 32) {
    bf16x8 a0 = *(const bf16x8*)(Ap + k0);
    bf16x8 a1 = *(const bf16x8*)(Ap + k0 + 8);
    bf16x8 b0 = *(const bf16x8*)(Bp + k0);
    bf16x8 b1 = *(const bf16x8*)(Bp + k0 + 8);
    __syncthreads();
    *(bf16x8*)&Al[srow * LDT + scol] = a0;
    *(bf16x8*)&Al[srow * LDT + scol + 8] = a1;
    *(bf16x8*)&Bl[srow * LDT + scol] = b0;
    *(bf16x8*)&Bl[srow * LDT + scol + 8] = b1;
    __syncthreads();
    bf16x8 af[4], bfr[4];
#pragma unroll
    for (int i = 0; i < 4; ++i) {
      af[i] = *(const bf16x8*)&Al[(wr * 64 + i * 16 + fr) * LDT + fk];
      bfr[i] = *(const bf16x8*)&Bl[(wc * 64 + i * 16 + fr) * LDT + fk];
    }
#pragma unroll
    for (int i = 0; i < 4; ++i)
#pragma unroll
      for (int j = 0; j < 4; ++j) acc[i][j] = MFMA(af[i], bfr[j], acc[i][j]);
  }
  int cr = (lane >> 4) << 2, cc = lane & 15;
#pragma unroll
  for (int j = 0; j < 4; ++j) {
    int col = col0 + wc * 64 + j * 16 + cc;
    float bb = (EPI >= 1) ? bias[col] : 0.f;
#pragma unroll
    for (int i = 0; i < 4; ++i) {
#pragma unroll
      for (int r = 0; r < 4; ++r) {
        size_t row = row0 + wr * 64 + i * 16 + cr + r;
        float v = acc[i][j][r] + bb;
        if (EPI == 2)
          ((float*)outp)[row * N + col] = v + resid[row * N + col];
        else
          ((unsigned short*)outp)[row * N + col] = f2bf(v);
      }
    }
  }
}

// ---------------- GEMM + GEGLU: g = gelu_tanh(h1) * h2 ----------------
// A = hr [8192 x 512], Bt = V_wi_t [8192 x 512] (rows: out-col), out g [8192 x 4096] bf16
__global__ __launch_bounds__(256) void k_gemm_geglu(const unsigned short* __restrict__ A,
                                                    const unsigned short* __restrict__ Bt,
                                                    const float* __restrict__ bias,
                                                    unsigned short* __restrict__ out) {
  __shared__ short Al[128 * LDT];
  __shared__ short B1l[128 * LDT];
  __shared__ short B2l[128 * LDT];
  const int K = 512;
  int tid = threadIdx.x, lane = tid & 63, wid = tid >> 6;
  int wr = wid >> 1, wc = wid & 1;
  size_t row0 = (size_t)blockIdx.y * 128;
  int col0 = blockIdx.x * 128;
  int srow = tid >> 1, scol = (tid & 1) << 4;
  const unsigned short* Ap = A + (row0 + srow) * K + scol;
  const unsigned short* B1p = Bt + (size_t)(col0 + srow) * K + scol;
  const unsigned short* B2p = Bt + (size_t)(col0 + 4096 + srow) * K + scol;
  f32x4 acc1[4][4] = {}, acc2[4][4] = {};
  int fr = lane & 15, fk = (lane >> 4) << 3;
  for (int k0 = 0; k0 < K; k0 += 32) {
    bf16x8 a0 = *(const bf16x8*)(Ap + k0);
    bf16x8 a1 = *(const bf16x8*)(Ap + k0 + 8);
    bf16x8 b10 = *(const bf16x8*)(B1p + k0);
    bf16x8 b11 = *(const bf16x8*)(B1p + k0 + 8);
    bf16x8 b20 = *(const bf16x8*)(B2p + k0);
    bf16x8 b21 = *(const bf16x8*)(B2p + k0 + 8);
    __syncthreads();
    *(bf16x8*)&Al[srow * LDT + scol] = a0;
    *(bf16x8*)&Al[srow * LDT + scol + 8] = a1;
    *(bf16x8*)&B1l[srow * LDT + scol] = b10;
    *(bf16x8*)&B1l[srow * LDT + scol + 8] = b11;
    *(bf16x8*)&B2l[srow * LDT + scol] = b20;
    *(bf16x8*)&B2l[srow * LDT + scol + 8] = b21;
    __syncthreads();
    bf16x8 af[4], b1f[4], b2f[4];
#pragma unroll
    for (int i = 0; i < 4; ++i) {
      af[i] = *(const bf16x8*)&Al[(wr * 64 + i * 16 + fr) * LDT + fk];
      b1f[i] = *(const bf16x8*)&B1l[(wc * 64 + i * 16 + fr) * LDT + fk];
      b2f[i] = *(const bf16x8*)&B2l[(wc * 64 + i * 16 + fr) * LDT + fk];
    }
#pragma unroll
    for (int i = 0; i < 4; ++i)
#pragma unroll
      for (int j = 0; j < 4; ++j) {
        acc1[i][j] = MFMA(af[i], b1f[j], acc1[i][j]);
        acc2[i][j] = MFMA(af[i], b2f[j], acc2[i][j]);
      }
  }
  int cr = (lane >> 4) << 2, cc = lane & 15;
#pragma unroll
  for (int j = 0; j < 4; ++j) {
    int col = col0 + wc * 64 + j * 16 + cc;
    float bb1 = bias[col], bb2 = bias[col + 4096];
#pragma unroll
    for (int i = 0; i < 4; ++i) {
#pragma unroll
      for (int r = 0; r < 4; ++r) {
        size_t row = row0 + wr * 64 + i * 16 + cr + r;
        float h1 = acc1[i][j][r] + bb1;
        float h2 = acc2[i][j][r] + bb2;
        float u = 0.7978845608028654f * (h1 + 0.044715f * h1 * h1 * h1);
        float e = __expf(2.f * u);
        float th = 1.f - 2.f / (e + 1.f);
        float gv = 0.5f * h1 * (1.f + th) * h2;
        out[row * 4096 + col] = f2bf(gv);
      }
    }
  }
}

// ---------------- RoPE in-place on qkv (+ Q scale 1/8) ----------------
// qkv token-major [8192][3072]; rotates q (proj 0) and k (proj 1) in place.
// Each thread owns one (x1,x2) pair -> race-free in-place.
__global__ void k_rope(unsigned short* __restrict__ qkv) {
  int idx = blockIdx.x * 256 + threadIdx.x;  // [0, 8192*1024)
  int tok = idx >> 10;
  int rem = idx & 1023;
  int isk = rem >> 9;
  int h = (rem >> 5) & 15;
  int i = rem & 31;
  int m = tok & 2047;
  size_t base = (size_t)tok * 3072 + (size_t)isk * 1024 + h * 64 + i;
  float x1 = bf2f(qkv[base]);
  float x2 = bf2f(qkv[base + 32]);
  float ang = (float)m * __expf((float)i * -0.28782313662425575f);  // ln(10000)/32
  float sn, cs;
  __sincosf(ang, &sn, &cs);
  float sc = isk ? 1.f : 0.125f;  // fold 1/sqrt(64) into Q
  qkv[base] = f2bf((x1 * cs - x2 * sn) * sc);
  qkv[base + 32] = f2bf((x2 * cs + x1 * sn) * sc);
}

// ---------------- flash attention ----------------
// grid (M/64, B*H); 4 waves, each owns 16 q rows. Q,K,V read from qkv (stride 3072).
// K staged [k][d], V staged transposed [d][k].
__global__ __launch_bounds__(256, 2) void k_attn(const unsigned short* __restrict__ qkv,
                                                 const int* __restrict__ mask,
                                                 unsigned short* __restrict__ ctx) {
  __shared__ short Kl[64 * 72];
  __shared__ short Vl[64 * 72];
  __shared__ float mpen[64];
  __shared__ short Pl[4][16 * 72];
  int bh = blockIdx.y, b = bh >> 4, h = bh & 15;
  int q0 = blockIdx.x << 6;
  int tid = threadIdx.x, lane = tid & 63, wid = tid >> 6;
  int fr = lane & 15, fk = (lane >> 4) << 3;
  const unsigned short* qbase =
      qkv + ((size_t)(b * 2048 + q0 + wid * 16 + fr)) * 3072 + h * 64;
  bf16x8 qa0 = *(const bf16x8*)(qbase + fk);
  bf16x8 qa1 = *(const bf16x8*)(qbase + 32 + fk);
  float m_r[4] = {-1e30f, -1e30f, -1e30f, -1e30f};
  float l_r[4] = {0.f, 0.f, 0.f, 0.f};
  f32x4 cacc[4] = {};
  int skrow = tid >> 2;
  int skcol = (tid & 3) << 4;
  const unsigned short* kbase = qkv + ((size_t)(b * 2048)) * 3072 + 1024 + h * 64;
  const unsigned short* vbase = qkv + ((size_t)(b * 2048)) * 3072 + 2048 + h * 64;
  const int* mbase = mask + b * 2048;
  const f32x4 zero4 = {0.f, 0.f, 0.f, 0.f};
  for (int k0 = 0; k0 < 2048; k0 += 64) {
    __syncthreads();
    bf16x8 kv0 = *(const bf16x8*)(kbase + (size_t)(k0 + skrow) * 3072 + skcol);
    bf16x8 kv1 = *(const bf16x8*)(kbase + (size_t)(k0 + skrow) * 3072 + skcol + 8);
    bf16x8 vv0 = *(const bf16x8*)(vbase + (size_t)(k0 + skrow) * 3072 + skcol);
    bf16x8 vv1 = *(const bf16x8*)(vbase + (size_t)(k0 + skrow) * 3072 + skcol + 8);
    *(bf16x8*)&Kl[skrow * 72 + skcol] = kv0;
    *(bf16x8*)&Kl[skrow * 72 + skcol + 8] = kv1;
#pragma unroll
    for (int e = 0; e < 8; ++e) {
      Vl[(skcol + e) * 72 + skrow] = vv0[e];
      Vl[(skcol + 8 + e) * 72 + skrow] = vv1[e];
    }
    if (tid < 64) mpen[tid] = (mbase[k0 + tid] == 0) ? -1e30f : 0.f;
    __syncthreads();
    // S = Q K^T (scale pre-folded into Q)
    f32x4 s[4];
#pragma unroll
    for (int kt = 0; kt < 4; ++kt) {
      bf16x8 kf0 = *(const bf16x8*)&Kl[(kt * 16 + fr) * 72 + fk];
      bf16x8 kf1 = *(const bf16x8*)&Kl[(kt * 16 + fr) * 72 + fk + 32];
      s[kt] = MFMA(qa0, kf0, zero4);
      s[kt] = MFMA(qa1, kf1, s[kt]);
    }
#pragma unroll
    for (int kt = 0; kt < 4; ++kt) {
      float pen = mpen[kt * 16 + fr];
#pragma unroll
      for (int r = 0; r < 4; ++r) s[kt][r] += pen;
    }
    // online softmax; row (lane>>4)*4+r lives across the 16 lanes sharing lane>>4
    float fac[4];
#pragma unroll
    for (int r = 0; r < 4; ++r) {
      float t = fmaxf(fmaxf(s[0][r], s[1][r]), fmaxf(s[2][r], s[3][r]));
#pragma unroll
      for (int o = 1; o < 16; o <<= 1) t = fmaxf(t, __shfl_xor(t, o));
      float mn = fmaxf(m_r[r], t);
      fac[r] = __expf(m_r[r] - mn);
      m_r[r] = mn;
    }
    float p[4][4];
#pragma unroll
    for (int kt = 0; kt < 4; ++kt)
#pragma unroll
      for (int r = 0; r < 4; ++r) p[kt][r] = __expf(s[kt][r] - m_r[r]);
#pragma unroll
    for (int r = 0; r < 4; ++r) {
      float t = p[0][r] + p[1][r] + p[2][r] + p[3][r];
#pragma unroll
      for (int o = 1; o < 16; o <<= 1) t += __shfl_xor(t, o);
      l_r[r] = l_r[r] * fac[r] + t;
    }
#pragma unroll
    for (int dt = 0; dt < 4; ++dt)
#pragma unroll
      for (int r = 0; r < 4; ++r) cacc[dt][r] *= fac[r];
    // P: D-layout -> LDS -> A-layout
    short* pw = &Pl[wid][0];
    int prow = (lane >> 4) << 2;
#pragma unroll
    for (int kt = 0; kt < 4; ++kt)
#pragma unroll
      for (int r = 0; r < 4; ++r)
        pw[(prow + r) * 72 + kt * 16 + fr] = (short)f2bf(p[kt][r]);
    __syncthreads();
    bf16x8 pa0 = *(const bf16x8*)&Pl[wid][fr * 72 + fk];
    bf16x8 pa1 = *(const bf16x8*)&Pl[wid][fr * 72 + fk + 32];
#pragma unroll
    for (int dt = 0; dt < 4; ++dt) {
      bf16x8 vf0 = *(const bf16x8*)&Vl[(dt * 16 + fr) * 72 + fk];
      bf16x8 vf1 = *(const bf16x8*)&Vl[(dt * 16 + fr) * 72 + fk + 32];
      cacc[dt] = MFMA(pa0, vf0, cacc[dt]);
      cacc[dt] = MFMA(pa1, vf1, cacc[dt]);
    }
  }
  unsigned short* obase = ctx + ((size_t)(b * 2048 + q0 + wid * 16)) * 1024 + h * 64;
  int prow = (lane >> 4) << 2;
#pragma unroll
  for (int dt = 0; dt < 4; ++dt)
#pragma unroll
    for (int r = 0; r < 4; ++r) {
      float v = cacc[dt][r] / l_r[r];
      obase[(size_t)(prow + r) * 1024 + dt * 16 + fr] = f2bf(v);
    }
}

// ---------------- launch ----------------
extern "C" void kernel_launch(void* const* d_in, const int* in_sizes, int n_in, void* d_out,
                              int out_size, void* d_ws, size_t ws_size, hipStream_t stream) {
  const float* x = (const float*)d_in[0];
  const int* amask = (const int*)d_in[1];
  const float* ln1w = (const float*)d_in[2];
  const float* ln1b = (const float*)d_in[3];
  const float* Uq = (const float*)d_in[4];
  const float* Vq = (const float*)d_in[5];
  const float* bq = (const float*)d_in[6];
  const float* Uk = (const float*)d_in[7];
  const float* Vk = (const float*)d_in[8];
  const float* bk = (const float*)d_in[9];
  const float* Uv = (const float*)d_in[10];
  const float* Vv = (const float*)d_in[11];
  const float* bv = (const float*)d_in[12];
  const float* Wo = (const float*)d_in[13];
  const float* bo = (const float*)d_in[14];
  const float* ln2w = (const float*)d_in[15];
  const float* ln2b = (const float*)d_in[16];
  const float* Uwi = (const float*)d_in[17];
  const float* Vwi = (const float*)d_in[18];
  const float* bwi = (const float*)d_in[19];
  const float* Uwo = (const float*)d_in[20];
  const float* Vwo = (const float*)d_in[21];
  const float* bwo = (const float*)d_in[22];

  char* ws = (char*)d_ws;
  size_t off = 0;
  auto alloc = [&](size_t bytes) {
    void* p = ws + off;
    off += (bytes + 255) & ~(size_t)255;
    return p;
  };
  // layout (~150 MB). g (64MB) aliases [qkv(48) + ctx(16)] which are dead by then.
  unsigned short* xn = (unsigned short*)alloc((size_t)8192 * 1024 * 2);   // also xn2
  unsigned short* Wqkv = (unsigned short*)alloc((size_t)3072 * 1024 * 2);
  float* bqkv = (float*)alloc(3072 * 4);
  unsigned short* Wob = (unsigned short*)alloc((size_t)1024 * 1024 * 2);
  unsigned short* Uwit = (unsigned short*)alloc((size_t)512 * 1024 * 2);
  unsigned short* Vwit = (unsigned short*)alloc((size_t)8192 * 512 * 2);
  unsigned short* Uwot = (unsigned short*)alloc((size_t)512 * 4096 * 2);
  unsigned short* Vwot = (unsigned short*)alloc((size_t)1024 * 512 * 2);
  unsigned short* qkv = (unsigned short*)alloc((size_t)8192 * 3072 * 2);
  unsigned short* ctx = (unsigned short*)alloc((size_t)8192 * 1024 * 2);
  float* x1 = (float*)alloc((size_t)8192 * 1024 * 4);
  unsigned short* hr = (unsigned short*)alloc((size_t)8192 * 512 * 2);
  unsigned short* gr = (unsigned short*)alloc((size_t)8192 * 512 * 2);
  unsigned short* g = qkv;         // alias: 8192*4096*2 = 64MB over qkv+ctx
  unsigned short* xn2 = xn;        // alias: xn dead after QKV gemm
  if (off > ws_size) return;       // fail clean (absmax) instead of faulting
  (void)in_sizes; (void)n_in; (void)out_size;

  dim3 tb(32, 8);
  // weight prep (runs every call; deterministic)
  k_build_wqkv<<<12288, 256, 0, stream>>>(Uq, Vq, Uk, Vk, Uv, Vv, Wqkv);
  k_concat_bias<<<12, 256, 0, stream>>>(bq, bk, bv, bqkv);
  k_f2bf<<<4096, 256, 0, stream>>>(Wo, Wob, 1024 * 1024);
  k_transpose_bf16<<<dim3(512 / 32, 1024 / 32), tb, 0, stream>>>(Uwi, Uwit, 1024, 512);
  k_transpose_bf16<<<dim3(8192 / 32, 512 / 32), tb, 0, stream>>>(Vwi, Vwit, 512, 8192);
  k_transpose_bf16<<<dim3(512 / 32, 4096 / 32), tb, 0, stream>>>(Uwo, Uwot, 4096, 512);
  k_transpose_bf16<<<dim3(1024 / 32, 512 / 32), tb, 0, stream>>>(Vwo, Vwot, 512, 1024);

  // block
  k_layernorm<<<8192, 256, 0, stream>>>(x, ln1w, ln1b, xn);
  k_gemm<1><<<dim3(24, 64), 256, 0, stream>>>(xn, Wqkv, bqkv, nullptr, qkv, 3072, 1024);
  k_rope<<<32768, 256, 0, stream>>>(qkv);
  k_attn<<<dim3(32, 64), 256, 0, stream>>>(qkv, amask, ctx);
  k_gemm<2><<<dim3(8, 64), 256, 0, stream>>>(ctx, Wob, bo, x, x1, 1024, 1024);
  k_layernorm<<<8192, 256, 0, stream>>>(x1, ln2w, ln2b, xn2);
  k_gemm<0><<<dim3(4, 64), 256, 0, stream>>>(xn2, Uwit, nullptr, nullptr, hr, 512, 1024);
  k_gemm_geglu<<<dim3(32, 64), 256, 0, stream>>>(hr, Vwit, bwi, g);
  k_gemm<0><<<dim3(4, 64), 256, 0, stream>>>(g, Uwot, nullptr, nullptr, gr, 512, 4096);
  k_gemm<2><<<dim3(8, 64), 256, 0, stream>>>(gr, Vwot, bwo, x1, d_out, 1024, 512);
}

// Round 3
// 766.559 us; speedup vs baseline: 1.0552x; 1.0552x over previous
//
#include <hip/hip_runtime.h>
#include <cstdint>

#define DEV __device__ __forceinline__

typedef __attribute__((ext_vector_type(8))) short bf16x8;
typedef __attribute__((ext_vector_type(4))) float f32x4;

#define MFMA(a,b,c) __builtin_amdgcn_mfma_f32_16x16x32_bf16((a),(b),(c),0,0,0)

DEV unsigned short f2bf(float f) {
  union { float f; unsigned u; } v; v.f = f;
  unsigned r = v.u + 0x7fffu + ((v.u >> 16) & 1u);
  return (unsigned short)(r >> 16);
}
DEV float bf2f(unsigned short s) {
  union { unsigned u; float f; } v; v.u = ((unsigned)s) << 16; return v.f;
}

// ---------------- prep kernels ----------------

// Wqkv_t[c3][d] = sum_r U[h][d][r]*V[h][r][k],  c3 = proj*1024 + h*64 + k
__global__ void k_build_wqkv(const float* __restrict__ Uq, const float* __restrict__ Vq,
                             const float* __restrict__ Uk, const float* __restrict__ Vk,
                             const float* __restrict__ Uv, const float* __restrict__ Vv,
                             unsigned short* __restrict__ W) {
  int idx = blockIdx.x * 256 + threadIdx.x;       // [0, 3072*1024)
  int d = idx & 1023;
  int c3 = idx >> 10;
  int proj = c3 >> 10;
  int c = c3 & 1023;
  int h = c >> 6, k = c & 63;
  const float* U = (proj == 0) ? Uq : (proj == 1) ? Uk : Uv;
  const float* V = (proj == 0) ? Vq : (proj == 1) ? Vk : Vv;
  const float* Urow = U + ((size_t)h * 1024 + d) * 32;
  const float* Vcol = V + (size_t)h * 32 * 64 + k;
  float s = 0.f;
#pragma unroll
  for (int r = 0; r < 32; ++r) s += Urow[r] * Vcol[r * 64];
  W[(size_t)c3 * 1024 + d] = f2bf(s);
}

__global__ void k_concat_bias(const float* __restrict__ bq, const float* __restrict__ bk,
                              const float* __restrict__ bv, float* __restrict__ out) {
  int i = blockIdx.x * 256 + threadIdx.x;
  if (i < 1024) out[i] = bq[i];
  else if (i < 2048) out[i] = bk[i - 1024];
  else if (i < 3072) out[i] = bv[i - 2048];
}

__global__ void k_f2bf(const float* __restrict__ in, unsigned short* __restrict__ out, int n) {
  int i = blockIdx.x * 256 + threadIdx.x;
  if (i < n) out[i] = f2bf(in[i]);
}

// fp32 [R][C] -> bf16 [C][R]
__global__ void k_transpose_bf16(const float* __restrict__ in, unsigned short* __restrict__ out,
                                 int R, int C) {
  __shared__ float tile[32][33];
  int c0 = blockIdx.x * 32, r0 = blockIdx.y * 32;
  int tx = threadIdx.x, ty = threadIdx.y;
#pragma unroll
  for (int i = ty; i < 32; i += 8)
    tile[i][tx] = in[(size_t)(r0 + i) * C + c0 + tx];
  __syncthreads();
#pragma unroll
  for (int i = ty; i < 32; i += 8)
    out[(size_t)(c0 + i) * R + r0 + tx] = f2bf(tile[tx][i]);
}

// bf16 V slice of qkv [tok][3072] -> vT[bh][d=64][m=2048]
__global__ __launch_bounds__(256) void k_vtrans(const unsigned short* __restrict__ qkv,
                                                unsigned short* __restrict__ vT) {
  __shared__ short t[64][66];
  int bh = blockIdx.y, b = bh >> 4, h = bh & 15;
  int m0 = blockIdx.x << 6;
  int tid = threadIdx.x;
  int rr = tid >> 2, cc = (tid & 3) << 4;
  const unsigned short* src = qkv + ((size_t)(b * 2048 + m0 + rr)) * 3072 + 2048 + h * 64 + cc;
  *(bf16x8*)&t[rr][cc] = *(const bf16x8*)src;
  *(bf16x8*)&t[rr][cc + 8] = *(const bf16x8*)(src + 8);
  __syncthreads();
  unsigned short* dst = vT + ((size_t)bh * 64 + rr) * 2048 + m0 + cc;
  bf16x8 o0, o1;
#pragma unroll
  for (int j = 0; j < 8; ++j) o0[j] = t[cc + j][rr];
#pragma unroll
  for (int j = 0; j < 8; ++j) o1[j] = t[cc + 8 + j][rr];
  *(bf16x8*)dst = o0;
  *(bf16x8*)(dst + 8) = o1;
}

// ---------------- layernorm (row = 1024 fp32 -> bf16) ----------------
__global__ __launch_bounds__(256) void k_layernorm(const float* __restrict__ x,
                                                   const float* __restrict__ w,
                                                   const float* __restrict__ b,
                                                   unsigned short* __restrict__ out) {
  int row = blockIdx.x;
  int tid = threadIdx.x;
  int lane = tid & 63, wid = tid >> 6;
  const float4 v = ((const float4*)(x + (size_t)row * 1024))[tid];
  float s = v.x + v.y + v.z + v.w;
  float s2 = v.x * v.x + v.y * v.y + v.z * v.z + v.w * v.w;
#pragma unroll
  for (int o = 1; o < 64; o <<= 1) { s += __shfl_xor(s, o); s2 += __shfl_xor(s2, o); }
  __shared__ float as_[4], as2_[4];
  if (lane == 0) { as_[wid] = s; as2_[wid] = s2; }
  __syncthreads();
  s = as_[0] + as_[1] + as_[2] + as_[3];
  s2 = as2_[0] + as2_[1] + as2_[2] + as2_[3];
  float mean = s * (1.f / 1024.f);
  float var = s2 * (1.f / 1024.f) - mean * mean;
  float inv = rsqrtf(var + 1e-5f);
  const float4 wv = ((const float4*)w)[tid];
  const float4 bv = ((const float4*)b)[tid];
  union { unsigned short u[4]; unsigned long long ll; } o;
  o.u[0] = f2bf((v.x - mean) * inv * wv.x + bv.x);
  o.u[1] = f2bf((v.y - mean) * inv * wv.y + bv.y);
  o.u[2] = f2bf((v.z - mean) * inv * wv.z + bv.z);
  o.u[3] = f2bf((v.w - mean) * inv * wv.w + bv.w);
  ((unsigned long long*)(out + (size_t)row * 1024))[tid] = o.ll;
}

// ---------------- GEMM: C[8192 x N] = A[8192 x K](bf16) * Bt[N x K]^T ----------------
// EPI 0: bf16 out;  1: bf16 out + bias;  2: f32 out + bias + resid
#define LDT 56

template <int EPI>
__global__ __launch_bounds__(256, 2) void k_gemm(const unsigned short* __restrict__ A,
                                                 const unsigned short* __restrict__ Bt,
                                                 const float* __restrict__ bias,
                                                 const float* __restrict__ resid,
                                                 void* __restrict__ outp, int N, int K) {
  __shared__ short Al[128 * LDT];
  __shared__ short Bl[128 * LDT];
  int tid = threadIdx.x, lane = tid & 63, wid = tid >> 6;
  int wr = wid >> 1, wc = wid & 1;
  size_t row0 = (size_t)blockIdx.y * 128;
  int col0 = blockIdx.x * 128;
  int srow = tid >> 1, scol = (tid & 1) << 4;
  const unsigned short* Ap = A + (row0 + srow) * K + scol;
  const unsigned short* Bp = Bt + (size_t)(col0 + srow) * K + scol;
  f32x4 acc[4][4] = {};
  int fr = lane & 15, fk = (lane >> 4) << 3;
  for (int k0 = 0; k0 < K; k0 += 32) {
    bf16x8 a0 = *(const bf16x8*)(Ap + k0);
    bf16x8 a1 = *(const bf16x8*)(Ap + k0 + 8);
    bf16x8 b0 = *(const bf16x8*)(Bp + k0);
    bf16x8 b1 = *(const bf16x8*)(Bp + k0 + 8);
    __syncthreads();
    *(bf16x8*)&Al[srow * LDT + scol] = a0;
    *(bf16x8*)&Al[srow * LDT + scol + 8] = a1;
    *(bf16x8*)&Bl[srow * LDT + scol] = b0;
    *(bf16x8*)&Bl[srow * LDT + scol + 8] = b1;
    __syncthreads();
    bf16x8 af[4], bfr[4];
#pragma unroll
    for (int i = 0; i < 4; ++i) {
      af[i] = *(const bf16x8*)&Al[(wr * 64 + i * 16 + fr) * LDT + fk];
      bfr[i] = *(const bf16x8*)&Bl[(wc * 64 + i * 16 + fr) * LDT + fk];
    }
#pragma unroll
    for (int i = 0; i < 4; ++i)
#pragma unroll
      for (int j = 0; j < 4; ++j) acc[i][j] = MFMA(af[i], bfr[j], acc[i][j]);
  }
  int cr = (lane >> 4) << 2, cc = lane & 15;
#pragma unroll
  for (int j = 0; j < 4; ++j) {
    int col = col0 + wc * 64 + j * 16 + cc;
    float bb = (EPI >= 1) ? bias[col] : 0.f;
#pragma unroll
    for (int i = 0; i < 4; ++i) {
#pragma unroll
      for (int r = 0; r < 4; ++r) {
        size_t row = row0 + wr * 64 + i * 16 + cr + r;
        float v = acc[i][j][r] + bb;
        if (EPI == 2)
          ((float*)outp)[row * N + col] = v + resid[row * N + col];
        else
          ((unsigned short*)outp)[row * N + col] = f2bf(v);
      }
    }
  }
}

// ---------------- GEMM + GEGLU: g = gelu_tanh(h1) * h2 ----------------
__global__ __launch_bounds__(256) void k_gemm_geglu(const unsigned short* __restrict__ A,
                                                    const unsigned short* __restrict__ Bt,
                                                    const float* __restrict__ bias,
                                                    unsigned short* __restrict__ out) {
  __shared__ short Al[128 * LDT];
  __shared__ short B1l[128 * LDT];
  __shared__ short B2l[128 * LDT];
  const int K = 512;
  int tid = threadIdx.x, lane = tid & 63, wid = tid >> 6;
  int wr = wid >> 1, wc = wid & 1;
  size_t row0 = (size_t)blockIdx.y * 128;
  int col0 = blockIdx.x * 128;
  int srow = tid >> 1, scol = (tid & 1) << 4;
  const unsigned short* Ap = A + (row0 + srow) * K + scol;
  const unsigned short* B1p = Bt + (size_t)(col0 + srow) * K + scol;
  const unsigned short* B2p = Bt + (size_t)(col0 + 4096 + srow) * K + scol;
  f32x4 acc1[4][4] = {}, acc2[4][4] = {};
  int fr = lane & 15, fk = (lane >> 4) << 3;
  for (int k0 = 0; k0 < K; k0 += 32) {
    bf16x8 a0 = *(const bf16x8*)(Ap + k0);
    bf16x8 a1 = *(const bf16x8*)(Ap + k0 + 8);
    bf16x8 b10 = *(const bf16x8*)(B1p + k0);
    bf16x8 b11 = *(const bf16x8*)(B1p + k0 + 8);
    bf16x8 b20 = *(const bf16x8*)(B2p + k0);
    bf16x8 b21 = *(const bf16x8*)(B2p + k0 + 8);
    __syncthreads();
    *(bf16x8*)&Al[srow * LDT + scol] = a0;
    *(bf16x8*)&Al[srow * LDT + scol + 8] = a1;
    *(bf16x8*)&B1l[srow * LDT + scol] = b10;
    *(bf16x8*)&B1l[srow * LDT + scol + 8] = b11;
    *(bf16x8*)&B2l[srow * LDT + scol] = b20;
    *(bf16x8*)&B2l[srow * LDT + scol + 8] = b21;
    __syncthreads();
    bf16x8 af[4], b1f[4], b2f[4];
#pragma unroll
    for (int i = 0; i < 4; ++i) {
      af[i] = *(const bf16x8*)&Al[(wr * 64 + i * 16 + fr) * LDT + fk];
      b1f[i] = *(const bf16x8*)&B1l[(wc * 64 + i * 16 + fr) * LDT + fk];
      b2f[i] = *(const bf16x8*)&B2l[(wc * 64 + i * 16 + fr) * LDT + fk];
    }
#pragma unroll
    for (int i = 0; i < 4; ++i)
#pragma unroll
      for (int j = 0; j < 4; ++j) {
        acc1[i][j] = MFMA(af[i], b1f[j], acc1[i][j]);
        acc2[i][j] = MFMA(af[i], b2f[j], acc2[i][j]);
      }
  }
  int cr = (lane >> 4) << 2, cc = lane & 15;
#pragma unroll
  for (int j = 0; j < 4; ++j) {
    int col = col0 + wc * 64 + j * 16 + cc;
    float bb1 = bias[col], bb2 = bias[col + 4096];
#pragma unroll
    for (int i = 0; i < 4; ++i) {
#pragma unroll
      for (int r = 0; r < 4; ++r) {
        size_t row = row0 + wr * 64 + i * 16 + cr + r;
        float h1 = acc1[i][j][r] + bb1;
        float h2 = acc2[i][j][r] + bb2;
        float u = 0.7978845608028654f * (h1 + 0.044715f * h1 * h1 * h1);
        float e = __expf(2.f * u);
        float th = 1.f - 2.f / (e + 1.f);
        float gv = 0.5f * h1 * (1.f + th) * h2;
        out[row * 4096 + col] = f2bf(gv);
      }
    }
  }
}

// ---------------- RoPE in-place on qkv (+ Q scale 1/8) ----------------
__global__ void k_rope(unsigned short* __restrict__ qkv) {
  int idx = blockIdx.x * 256 + threadIdx.x;  // [0, 8192*1024)
  int tok = idx >> 10;
  int rem = idx & 1023;
  int isk = rem >> 9;
  int h = (rem >> 5) & 15;
  int i = rem & 31;
  int m = tok & 2047;
  size_t base = (size_t)tok * 3072 + (size_t)isk * 1024 + h * 64 + i;
  float x1 = bf2f(qkv[base]);
  float x2 = bf2f(qkv[base + 32]);
  float ang = (float)m * __expf((float)i * -0.28782313662425575f);  // ln(10000)/32
  float sn, cs;
  __sincosf(ang, &sn, &cs);
  float sc = isk ? 1.f : 0.125f;  // fold 1/sqrt(64) into Q
  qkv[base] = f2bf((x1 * cs - x2 * sn) * sc);
  qkv[base + 32] = f2bf((x2 * cs + x1 * sn) * sc);
}

// ---------------- flash attention ----------------
// grid (M/64, B*H); 4 waves x 16 q rows. K from qkv (row-major), V from vT (pre-transposed).
// K/V tiles in LDS with XOR swizzle (T2), next tile prefetched in regs (T14).
#define KIX(r, c) ((r) * 64 + ((c) ^ (((r) & 7) << 3)))

__global__ __launch_bounds__(256, 2) void k_attn(const unsigned short* __restrict__ qkv,
                                                 const unsigned short* __restrict__ vT,
                                                 const int* __restrict__ mask,
                                                 unsigned short* __restrict__ ctx) {
  __shared__ short Kl[64 * 64];
  __shared__ short Vl[64 * 64];
  __shared__ float mpen[64];
  __shared__ short Pl[4][16 * 72];
  int bh = blockIdx.y, b = bh >> 4, h = bh & 15;
  int q0 = blockIdx.x << 6;
  int tid = threadIdx.x, lane = tid & 63, wid = tid >> 6;
  int fr = lane & 15, fk = (lane >> 4) << 3;
  const unsigned short* qbase =
      qkv + ((size_t)(b * 2048 + q0 + wid * 16 + fr)) * 3072 + h * 64;
  bf16x8 qa0 = *(const bf16x8*)(qbase + fk);
  bf16x8 qa1 = *(const bf16x8*)(qbase + 32 + fk);
  float m_r[4] = {-1e30f, -1e30f, -1e30f, -1e30f};
  float l_r[4] = {0.f, 0.f, 0.f, 0.f};
  f32x4 cacc[4] = {};
  int srow = tid >> 2;            // staging row (kv for K, d for V^T)
  int sc = (tid & 3) << 4;        // staging col (shorts)
  const unsigned short* kb =
      qkv + ((size_t)(b * 2048 + srow)) * 3072 + 1024 + h * 64 + sc;
  const unsigned short* vb = vT + ((size_t)bh * 64 + srow) * 2048 + sc;
  const int* mbase = mask + b * 2048;
  const f32x4 zero4 = {0.f, 0.f, 0.f, 0.f};
  // prefetch tile 0
  bf16x8 kn0 = *(const bf16x8*)kb;
  bf16x8 kn1 = *(const bf16x8*)(kb + 8);
  bf16x8 vn0 = *(const bf16x8*)vb;
  bf16x8 vn1 = *(const bf16x8*)(vb + 8);
  int mv = (tid < 64) ? mbase[tid] : 1;
  for (int k0 = 0; k0 < 2048; k0 += 64) {
    __syncthreads();  // prior tile's LDS reads drained
    *(bf16x8*)&Kl[KIX(srow, sc)] = kn0;
    *(bf16x8*)&Kl[KIX(srow, sc + 8)] = kn1;
    *(bf16x8*)&Vl[KIX(srow, sc)] = vn0;
    *(bf16x8*)&Vl[KIX(srow, sc + 8)] = vn1;
    if (tid < 64) mpen[tid] = (mv == 0) ? -1e30f : 0.f;
    if (k0 + 64 < 2048) {  // prefetch next tile (hidden under compute)
      kn0 = *(const bf16x8*)(kb + (size_t)(k0 + 64) * 3072);
      kn1 = *(const bf16x8*)(kb + (size_t)(k0 + 64) * 3072 + 8);
      vn0 = *(const bf16x8*)(vb + k0 + 64);
      vn1 = *(const bf16x8*)(vb + k0 + 64 + 8);
      mv = (tid < 64) ? mbase[k0 + 64 + tid] : 1;
    }
    __syncthreads();
    // S = Q K^T (scale pre-folded into Q)
    f32x4 s[4];
#pragma unroll
    for (int kt = 0; kt < 4; ++kt) {
      bf16x8 kf0 = *(const bf16x8*)&Kl[KIX(kt * 16 + fr, fk)];
      bf16x8 kf1 = *(const bf16x8*)&Kl[KIX(kt * 16 + fr, fk + 32)];
      s[kt] = MFMA(qa0, kf0, zero4);
      s[kt] = MFMA(qa1, kf1, s[kt]);
    }
#pragma unroll
    for (int kt = 0; kt < 4; ++kt) {
      float pen = mpen[kt * 16 + fr];
#pragma unroll
      for (int r = 0; r < 4; ++r) s[kt][r] += pen;
    }
    // online softmax; row (lane>>4)*4+r lives across the 16 lanes sharing lane>>4
    float fac[4];
#pragma unroll
    for (int r = 0; r < 4; ++r) {
      float t = fmaxf(fmaxf(s[0][r], s[1][r]), fmaxf(s[2][r], s[3][r]));
#pragma unroll
      for (int o = 1; o < 16; o <<= 1) t = fmaxf(t, __shfl_xor(t, o));
      float mn = fmaxf(m_r[r], t);
      fac[r] = __expf(m_r[r] - mn);
      m_r[r] = mn;
    }
    float p[4][4];
#pragma unroll
    for (int kt = 0; kt < 4; ++kt)
#pragma unroll
      for (int r = 0; r < 4; ++r) p[kt][r] = __expf(s[kt][r] - m_r[r]);
#pragma unroll
    for (int r = 0; r < 4; ++r) {
      float t = p[0][r] + p[1][r] + p[2][r] + p[3][r];
#pragma unroll
      for (int o = 1; o < 16; o <<= 1) t += __shfl_xor(t, o);
      l_r[r] = l_r[r] * fac[r] + t;
    }
#pragma unroll
    for (int dt = 0; dt < 4; ++dt)
#pragma unroll
      for (int r = 0; r < 4; ++r) cacc[dt][r] *= fac[r];
    // P: D-layout -> LDS -> A-layout (per-wave region)
    short* pw = &Pl[wid][0];
    int prow = (lane >> 4) << 2;
#pragma unroll
    for (int kt = 0; kt < 4; ++kt)
#pragma unroll
      for (int r = 0; r < 4; ++r)
        pw[(prow + r) * 72 + kt * 16 + fr] = (short)f2bf(p[kt][r]);
    __syncthreads();
    bf16x8 pa0 = *(const bf16x8*)&Pl[wid][fr * 72 + fk];
    bf16x8 pa1 = *(const bf16x8*)&Pl[wid][fr * 72 + fk + 32];
#pragma unroll
    for (int dt = 0; dt < 4; ++dt) {
      bf16x8 vf0 = *(const bf16x8*)&Vl[KIX(dt * 16 + fr, fk)];
      bf16x8 vf1 = *(const bf16x8*)&Vl[KIX(dt * 16 + fr, fk + 32)];
      cacc[dt] = MFMA(pa0, vf0, cacc[dt]);
      cacc[dt] = MFMA(pa1, vf1, cacc[dt]);
    }
  }
  unsigned short* obase = ctx + ((size_t)(b * 2048 + q0 + wid * 16)) * 1024 + h * 64;
  int prow = (lane >> 4) << 2;
#pragma unroll
  for (int dt = 0; dt < 4; ++dt)
#pragma unroll
    for (int r = 0; r < 4; ++r) {
      float v = cacc[dt][r] / l_r[r];
      obase[(size_t)(prow + r) * 1024 + dt * 16 + fr] = f2bf(v);
    }
}

// ---------------- launch ----------------
extern "C" void kernel_launch(void* const* d_in, const int* in_sizes, int n_in, void* d_out,
                              int out_size, void* d_ws, size_t ws_size, hipStream_t stream) {
  const float* x = (const float*)d_in[0];
  const int* amask = (const int*)d_in[1];
  const float* ln1w = (const float*)d_in[2];
  const float* ln1b = (const float*)d_in[3];
  const float* Uq = (const float*)d_in[4];
  const float* Vq = (const float*)d_in[5];
  const float* bq = (const float*)d_in[6];
  const float* Uk = (const float*)d_in[7];
  const float* Vk = (const float*)d_in[8];
  const float* bk = (const float*)d_in[9];
  const float* Uv = (const float*)d_in[10];
  const float* Vv = (const float*)d_in[11];
  const float* bv = (const float*)d_in[12];
  const float* Wo = (const float*)d_in[13];
  const float* bo = (const float*)d_in[14];
  const float* ln2w = (const float*)d_in[15];
  const float* ln2b = (const float*)d_in[16];
  const float* Uwi = (const float*)d_in[17];
  const float* Vwi = (const float*)d_in[18];
  const float* bwi = (const float*)d_in[19];
  const float* Uwo = (const float*)d_in[20];
  const float* Vwo = (const float*)d_in[21];
  const float* bwo = (const float*)d_in[22];

  char* ws = (char*)d_ws;
  size_t off = 0;
  auto alloc = [&](size_t bytes) {
    void* p = ws + off;
    off += (bytes + 255) & ~(size_t)255;
    return p;
  };
  // layout (~150 MB). g (64MB) aliases [qkv+ctx]; vT (16MB) aliases x1 (both dead then).
  unsigned short* xn = (unsigned short*)alloc((size_t)8192 * 1024 * 2);   // also xn2
  unsigned short* Wqkv = (unsigned short*)alloc((size_t)3072 * 1024 * 2);
  float* bqkv = (float*)alloc(3072 * 4);
  unsigned short* Wob = (unsigned short*)alloc((size_t)1024 * 1024 * 2);
  unsigned short* Uwit = (unsigned short*)alloc((size_t)512 * 1024 * 2);
  unsigned short* Vwit = (unsigned short*)alloc((size_t)8192 * 512 * 2);
  unsigned short* Uwot = (unsigned short*)alloc((size_t)512 * 4096 * 2);
  unsigned short* Vwot = (unsigned short*)alloc((size_t)1024 * 512 * 2);
  unsigned short* qkv = (unsigned short*)alloc((size_t)8192 * 3072 * 2);
  unsigned short* ctx = (unsigned short*)alloc((size_t)8192 * 1024 * 2);
  float* x1 = (float*)alloc((size_t)8192 * 1024 * 4);
  unsigned short* hr = (unsigned short*)alloc((size_t)8192 * 512 * 2);
  unsigned short* gr = (unsigned short*)alloc((size_t)8192 * 512 * 2);
  unsigned short* g = qkv;                 // alias: 64MB over qkv+ctx (dead by FFN)
  unsigned short* xn2 = xn;                // alias: xn dead after QKV gemm
  unsigned short* vT = (unsigned short*)x1;  // alias: x1 written only after attn
  if (off > ws_size) return;               // fail clean instead of faulting
  (void)in_sizes; (void)n_in; (void)out_size;

  dim3 tb(32, 8);
  // weight prep (runs every call; deterministic)
  k_build_wqkv<<<12288, 256, 0, stream>>>(Uq, Vq, Uk, Vk, Uv, Vv, Wqkv);
  k_concat_bias<<<12, 256, 0, stream>>>(bq, bk, bv, bqkv);
  k_f2bf<<<4096, 256, 0, stream>>>(Wo, Wob, 1024 * 1024);
  k_transpose_bf16<<<dim3(512 / 32, 1024 / 32), tb, 0, stream>>>(Uwi, Uwit, 1024, 512);
  k_transpose_bf16<<<dim3(8192 / 32, 512 / 32), tb, 0, stream>>>(Vwi, Vwit, 512, 8192);
  k_transpose_bf16<<<dim3(512 / 32, 4096 / 32), tb, 0, stream>>>(Uwo, Uwot, 4096, 512);
  k_transpose_bf16<<<dim3(1024 / 32, 512 / 32), tb, 0, stream>>>(Vwo, Vwot, 512, 1024);

  // block
  k_layernorm<<<8192, 256, 0, stream>>>(x, ln1w, ln1b, xn);
  k_gemm<1><<<dim3(24, 64), 256, 0, stream>>>(xn, Wqkv, bqkv, nullptr, qkv, 3072, 1024);
  k_rope<<<32768, 256, 0, stream>>>(qkv);
  k_vtrans<<<dim3(32, 64), 256, 0, stream>>>(qkv, vT);
  k_attn<<<dim3(32, 64), 256, 0, stream>>>(qkv, vT, amask, ctx);
  k_gemm<2><<<dim3(8, 64), 256, 0, stream>>>(ctx, Wob, bo, x, x1, 1024, 1024);
  k_layernorm<<<8192, 256, 0, stream>>>(x1, ln2w, ln2b, xn2);
  k_gemm<0><<<dim3(4, 64), 256, 0, stream>>>(xn2, Uwit, nullptr, nullptr, hr, 512, 1024);
  k_gemm_geglu<<<dim3(32, 64), 256, 0, stream>>>(hr, Vwit, bwi, g);
  k_gemm<0><<<dim3(4, 64), 256, 0, stream>>>(g, Uwot, nullptr, nullptr, gr, 512, 4096);
  k_gemm<2><<<dim3(8, 64), 256, 0, stream>>>(gr, Vwot, bwo, x1, d_out, 1024, 512);
}

// Round 4
// 722.679 us; speedup vs baseline: 1.1192x; 1.0607x over previous
//
#include <hip/hip_runtime.h>
#include <cstdint>

#define DEV __device__ __forceinline__

typedef __attribute__((ext_vector_type(8))) short bf16x8;
typedef __attribute__((ext_vector_type(4))) float f32x4;

#define MFMA(a,b,c) __builtin_amdgcn_mfma_f32_16x16x32_bf16((a),(b),(c),0,0,0)

DEV unsigned short f2bf(float f) {
  union { float f; unsigned u; } v; v.f = f;
  unsigned r = v.u + 0x7fffu + ((v.u >> 16) & 1u);
  return (unsigned short)(r >> 16);
}
DEV float bf2f(unsigned short s) {
  union { unsigned u; float f; } v; v.u = ((unsigned)s) << 16; return v.f;
}

// ---------------- prep kernels ----------------

// Wqkv_t[c3][d] = sum_r U[h][d][r]*V[h][r][k],  c3 = proj*1024 + h*64 + k
__global__ void k_build_wqkv(const float* __restrict__ Uq, const float* __restrict__ Vq,
                             const float* __restrict__ Uk, const float* __restrict__ Vk,
                             const float* __restrict__ Uv, const float* __restrict__ Vv,
                             unsigned short* __restrict__ W) {
  int idx = blockIdx.x * 256 + threadIdx.x;       // [0, 3072*1024)
  int d = idx & 1023;
  int c3 = idx >> 10;
  int proj = c3 >> 10;
  int c = c3 & 1023;
  int h = c >> 6, k = c & 63;
  const float* U = (proj == 0) ? Uq : (proj == 1) ? Uk : Uv;
  const float* V = (proj == 0) ? Vq : (proj == 1) ? Vk : Vv;
  const float* Urow = U + ((size_t)h * 1024 + d) * 32;
  const float* Vcol = V + (size_t)h * 32 * 64 + k;
  float s = 0.f;
#pragma unroll
  for (int r = 0; r < 32; ++r) s += Urow[r] * Vcol[r * 64];
  W[(size_t)c3 * 1024 + d] = f2bf(s);
}

__global__ void k_concat_bias(const float* __restrict__ bq, const float* __restrict__ bk,
                              const float* __restrict__ bv, float* __restrict__ out) {
  int i = blockIdx.x * 256 + threadIdx.x;
  if (i < 1024) out[i] = bq[i];
  else if (i < 2048) out[i] = bk[i - 1024];
  else if (i < 3072) out[i] = bv[i - 2048];
}

__global__ void k_f2bf(const float* __restrict__ in, unsigned short* __restrict__ out, int n) {
  int i = blockIdx.x * 256 + threadIdx.x;
  if (i < n) out[i] = f2bf(in[i]);
}

// fp32 [R][C] -> bf16 [C][R]
__global__ void k_transpose_bf16(const float* __restrict__ in, unsigned short* __restrict__ out,
                                 int R, int C) {
  __shared__ float tile[32][33];
  int c0 = blockIdx.x * 32, r0 = blockIdx.y * 32;
  int tx = threadIdx.x, ty = threadIdx.y;
#pragma unroll
  for (int i = ty; i < 32; i += 8)
    tile[i][tx] = in[(size_t)(r0 + i) * C + c0 + tx];
  __syncthreads();
#pragma unroll
  for (int i = ty; i < 32; i += 8)
    out[(size_t)(c0 + i) * R + r0 + tx] = f2bf(tile[tx][i]);
}

// bf16 V slice of qkv [tok][3072] -> vT[bh][d=64][m=2048]
__global__ __launch_bounds__(256) void k_vtrans(const unsigned short* __restrict__ qkv,
                                                unsigned short* __restrict__ vT) {
  __shared__ short t[64][66];
  int bh = blockIdx.y, b = bh >> 4, h = bh & 15;
  int m0 = blockIdx.x << 6;
  int tid = threadIdx.x;
  int rr = tid >> 2, cc = (tid & 3) << 4;
  const unsigned short* src = qkv + ((size_t)(b * 2048 + m0 + rr)) * 3072 + 2048 + h * 64 + cc;
  *(bf16x8*)&t[rr][cc] = *(const bf16x8*)src;
  *(bf16x8*)&t[rr][cc + 8] = *(const bf16x8*)(src + 8);
  __syncthreads();
  unsigned short* dst = vT + ((size_t)bh * 64 + rr) * 2048 + m0 + cc;
  bf16x8 o0, o1;
#pragma unroll
  for (int j = 0; j < 8; ++j) o0[j] = t[cc + j][rr];
#pragma unroll
  for (int j = 0; j < 8; ++j) o1[j] = t[cc + 8 + j][rr];
  *(bf16x8*)dst = o0;
  *(bf16x8*)(dst + 8) = o1;
}

// ---------------- layernorm (row = 1024 fp32 -> bf16) ----------------
__global__ __launch_bounds__(256) void k_layernorm(const float* __restrict__ x,
                                                   const float* __restrict__ w,
                                                   const float* __restrict__ b,
                                                   unsigned short* __restrict__ out) {
  int row = blockIdx.x;
  int tid = threadIdx.x;
  int lane = tid & 63, wid = tid >> 6;
  const float4 v = ((const float4*)(x + (size_t)row * 1024))[tid];
  float s = v.x + v.y + v.z + v.w;
  float s2 = v.x * v.x + v.y * v.y + v.z * v.z + v.w * v.w;
#pragma unroll
  for (int o = 1; o < 64; o <<= 1) { s += __shfl_xor(s, o); s2 += __shfl_xor(s2, o); }
  __shared__ float as_[4], as2_[4];
  if (lane == 0) { as_[wid] = s; as2_[wid] = s2; }
  __syncthreads();
  s = as_[0] + as_[1] + as_[2] + as_[3];
  s2 = as2_[0] + as2_[1] + as2_[2] + as2_[3];
  float mean = s * (1.f / 1024.f);
  float var = s2 * (1.f / 1024.f) - mean * mean;
  float inv = rsqrtf(var + 1e-5f);
  const float4 wv = ((const float4*)w)[tid];
  const float4 bv = ((const float4*)b)[tid];
  union { unsigned short u[4]; unsigned long long ll; } o;
  o.u[0] = f2bf((v.x - mean) * inv * wv.x + bv.x);
  o.u[1] = f2bf((v.y - mean) * inv * wv.y + bv.y);
  o.u[2] = f2bf((v.z - mean) * inv * wv.z + bv.z);
  o.u[3] = f2bf((v.w - mean) * inv * wv.w + bv.w);
  ((unsigned long long*)(out + (size_t)row * 1024))[tid] = o.ll;
}

// ---------------- GEMM: C[8192 x N] = A[8192 x K](bf16) * Bt[N x K]^T ----------------
// EPI 0: bf16 out;  1: bf16 out + bias;  2: f32 out + bias + resid
#define LDT 56

template <int EPI>
__global__ __launch_bounds__(256, 2) void k_gemm(const unsigned short* __restrict__ A,
                                                 const unsigned short* __restrict__ Bt,
                                                 const float* __restrict__ bias,
                                                 const float* __restrict__ resid,
                                                 void* __restrict__ outp, int N, int K) {
  __shared__ short Al[128 * LDT];
  __shared__ short Bl[128 * LDT];
  int tid = threadIdx.x, lane = tid & 63, wid = tid >> 6;
  int wr = wid >> 1, wc = wid & 1;
  size_t row0 = (size_t)blockIdx.y * 128;
  int col0 = blockIdx.x * 128;
  int srow = tid >> 1, scol = (tid & 1) << 4;
  const unsigned short* Ap = A + (row0 + srow) * K + scol;
  const unsigned short* Bp = Bt + (size_t)(col0 + srow) * K + scol;
  f32x4 acc[4][4] = {};
  int fr = lane & 15, fk = (lane >> 4) << 3;
  for (int k0 = 0; k0 < K; k0 += 32) {
    bf16x8 a0 = *(const bf16x8*)(Ap + k0);
    bf16x8 a1 = *(const bf16x8*)(Ap + k0 + 8);
    bf16x8 b0 = *(const bf16x8*)(Bp + k0);
    bf16x8 b1 = *(const bf16x8*)(Bp + k0 + 8);
    __syncthreads();
    *(bf16x8*)&Al[srow * LDT + scol] = a0;
    *(bf16x8*)&Al[srow * LDT + scol + 8] = a1;
    *(bf16x8*)&Bl[srow * LDT + scol] = b0;
    *(bf16x8*)&Bl[srow * LDT + scol + 8] = b1;
    __syncthreads();
    bf16x8 af[4], bfr[4];
#pragma unroll
    for (int i = 0; i < 4; ++i) {
      af[i] = *(const bf16x8*)&Al[(wr * 64 + i * 16 + fr) * LDT + fk];
      bfr[i] = *(const bf16x8*)&Bl[(wc * 64 + i * 16 + fr) * LDT + fk];
    }
#pragma unroll
    for (int i = 0; i < 4; ++i)
#pragma unroll
      for (int j = 0; j < 4; ++j) acc[i][j] = MFMA(af[i], bfr[j], acc[i][j]);
  }
  int cr = (lane >> 4) << 2, cc = lane & 15;
#pragma unroll
  for (int j = 0; j < 4; ++j) {
    int col = col0 + wc * 64 + j * 16 + cc;
    float bb = (EPI >= 1) ? bias[col] : 0.f;
#pragma unroll
    for (int i = 0; i < 4; ++i) {
#pragma unroll
      for (int r = 0; r < 4; ++r) {
        size_t row = row0 + wr * 64 + i * 16 + cr + r;
        float v = acc[i][j][r] + bb;
        if (EPI == 2)
          ((float*)outp)[row * N + col] = v + resid[row * N + col];
        else
          ((unsigned short*)outp)[row * N + col] = f2bf(v);
      }
    }
  }
}

// ---------------- GEMM + GEGLU: g = gelu_tanh(h1) * h2 ----------------
__global__ __launch_bounds__(256) void k_gemm_geglu(const unsigned short* __restrict__ A,
                                                    const unsigned short* __restrict__ Bt,
                                                    const float* __restrict__ bias,
                                                    unsigned short* __restrict__ out) {
  __shared__ short Al[128 * LDT];
  __shared__ short B1l[128 * LDT];
  __shared__ short B2l[128 * LDT];
  const int K = 512;
  int tid = threadIdx.x, lane = tid & 63, wid = tid >> 6;
  int wr = wid >> 1, wc = wid & 1;
  size_t row0 = (size_t)blockIdx.y * 128;
  int col0 = blockIdx.x * 128;
  int srow = tid >> 1, scol = (tid & 1) << 4;
  const unsigned short* Ap = A + (row0 + srow) * K + scol;
  const unsigned short* B1p = Bt + (size_t)(col0 + srow) * K + scol;
  const unsigned short* B2p = Bt + (size_t)(col0 + 4096 + srow) * K + scol;
  f32x4 acc1[4][4] = {}, acc2[4][4] = {};
  int fr = lane & 15, fk = (lane >> 4) << 3;
  for (int k0 = 0; k0 < K; k0 += 32) {
    bf16x8 a0 = *(const bf16x8*)(Ap + k0);
    bf16x8 a1 = *(const bf16x8*)(Ap + k0 + 8);
    bf16x8 b10 = *(const bf16x8*)(B1p + k0);
    bf16x8 b11 = *(const bf16x8*)(B1p + k0 + 8);
    bf16x8 b20 = *(const bf16x8*)(B2p + k0);
    bf16x8 b21 = *(const bf16x8*)(B2p + k0 + 8);
    __syncthreads();
    *(bf16x8*)&Al[srow * LDT + scol] = a0;
    *(bf16x8*)&Al[srow * LDT + scol + 8] = a1;
    *(bf16x8*)&B1l[srow * LDT + scol] = b10;
    *(bf16x8*)&B1l[srow * LDT + scol + 8] = b11;
    *(bf16x8*)&B2l[srow * LDT + scol] = b20;
    *(bf16x8*)&B2l[srow * LDT + scol + 8] = b21;
    __syncthreads();
    bf16x8 af[4], b1f[4], b2f[4];
#pragma unroll
    for (int i = 0; i < 4; ++i) {
      af[i] = *(const bf16x8*)&Al[(wr * 64 + i * 16 + fr) * LDT + fk];
      b1f[i] = *(const bf16x8*)&B1l[(wc * 64 + i * 16 + fr) * LDT + fk];
      b2f[i] = *(const bf16x8*)&B2l[(wc * 64 + i * 16 + fr) * LDT + fk];
    }
#pragma unroll
    for (int i = 0; i < 4; ++i)
#pragma unroll
      for (int j = 0; j < 4; ++j) {
        acc1[i][j] = MFMA(af[i], b1f[j], acc1[i][j]);
        acc2[i][j] = MFMA(af[i], b2f[j], acc2[i][j]);
      }
  }
  int cr = (lane >> 4) << 2, cc = lane & 15;
#pragma unroll
  for (int j = 0; j < 4; ++j) {
    int col = col0 + wc * 64 + j * 16 + cc;
    float bb1 = bias[col], bb2 = bias[col + 4096];
#pragma unroll
    for (int i = 0; i < 4; ++i) {
#pragma unroll
      for (int r = 0; r < 4; ++r) {
        size_t row = row0 + wr * 64 + i * 16 + cr + r;
        float h1 = acc1[i][j][r] + bb1;
        float h2 = acc2[i][j][r] + bb2;
        float u = 0.7978845608028654f * (h1 + 0.044715f * h1 * h1 * h1);
        float e = __expf(2.f * u);
        float th = 1.f - 2.f / (e + 1.f);
        float gv = 0.5f * h1 * (1.f + th) * h2;
        out[row * 4096 + col] = f2bf(gv);
      }
    }
  }
}

// ---------------- RoPE in-place on qkv ----------------
// Q scale folds 1/sqrt(64) AND log2(e) (softmax uses exp2).
__global__ void k_rope(unsigned short* __restrict__ qkv) {
  int idx = blockIdx.x * 256 + threadIdx.x;  // [0, 8192*1024)
  int tok = idx >> 10;
  int rem = idx & 1023;
  int isk = rem >> 9;
  int h = (rem >> 5) & 15;
  int i = rem & 31;
  int m = tok & 2047;
  size_t base = (size_t)tok * 3072 + (size_t)isk * 1024 + h * 64 + i;
  float x1 = bf2f(qkv[base]);
  float x2 = bf2f(qkv[base + 32]);
  float ang = (float)m * __expf((float)i * -0.28782313662425575f);  // ln(10000)/32
  float sn, cs;
  __sincosf(ang, &sn, &cs);
  float sc = isk ? 1.f : 0.18033688011112042f;  // 0.125 * log2(e)
  qkv[base] = f2bf((x1 * cs - x2 * sn) * sc);
  qkv[base + 32] = f2bf((x2 * cs + x1 * sn) * sc);
}

// ---------------- flash attention (swapped-operand, in-register softmax) ----------------
// grid (M/64, B*H); 4 waves x 16 q rows. S^T = MFMA(K,Q): col=lane&15=q, so each
// q-column's k-values are in-lane -> softmax = in-lane reduce + 2 shfl_xor.
// PV as O^T = MFMA(V^T, P); P redistributed D-layout->B-layout via cvt_pk + bpermute.
#define KIX(r, c) ((r) * 64 + ((c) ^ (((r) & 7) << 3)))

__global__ __launch_bounds__(256, 4) void k_attn(const unsigned short* __restrict__ qkv,
                                                 const unsigned short* __restrict__ vT,
                                                 const int* __restrict__ mask,
                                                 unsigned short* __restrict__ ctx) {
  __shared__ short Kl[64 * 64];
  __shared__ short Vl[64 * 64];
  __shared__ float mpen[64];
  int bh = blockIdx.y, b = bh >> 4, h = bh & 15;
  int q0 = blockIdx.x << 6;
  int tid = threadIdx.x, lane = tid & 63, wid = tid >> 6;
  int fr = lane & 15, fk = (lane >> 4) << 3;
  int g = lane >> 4, qi = lane & 15;
  const unsigned short* qbase =
      qkv + ((size_t)(b * 2048 + q0 + wid * 16 + fr)) * 3072 + h * 64;
  bf16x8 qa0 = *(const bf16x8*)(qbase + fk);
  bf16x8 qa1 = *(const bf16x8*)(qbase + 32 + fk);
  float m_r = -1e30f, l_r = 0.f;
  f32x4 cacc[4] = {};
  int srow = tid >> 2;
  int sc = (tid & 3) << 4;
  const unsigned short* kb =
      qkv + ((size_t)(b * 2048 + srow)) * 3072 + 1024 + h * 64 + sc;
  const unsigned short* vb = vT + ((size_t)bh * 64 + srow) * 2048 + sc;
  const int* mbase = mask + b * 2048;
  const f32x4 zero4 = {0.f, 0.f, 0.f, 0.f};
  // bpermute byte-addresses for P redistribution (hoisted)
  int addrA = (((g & 1) << 5) + qi) << 2;  // src lane (g&1)*32 + q
  int addrB = addrA + 64;                  // +16 lanes
  bool hi = ((g >> 1) & 1) != 0;
  // prefetch tile 0
  bf16x8 kn0 = *(const bf16x8*)kb;
  bf16x8 kn1 = *(const bf16x8*)(kb + 8);
  bf16x8 vn0 = *(const bf16x8*)vb;
  bf16x8 vn1 = *(const bf16x8*)(vb + 8);
  int mv = (tid < 64) ? mbase[tid] : 1;
  for (int k0 = 0; k0 < 2048; k0 += 64) {
    __syncthreads();  // prior tile's LDS reads drained
    *(bf16x8*)&Kl[KIX(srow, sc)] = kn0;
    *(bf16x8*)&Kl[KIX(srow, sc + 8)] = kn1;
    *(bf16x8*)&Vl[KIX(srow, sc)] = vn0;
    *(bf16x8*)&Vl[KIX(srow, sc + 8)] = vn1;
    if (tid < 64) mpen[tid] = (mv == 0) ? -1e30f : 0.f;
    if (k0 + 64 < 2048) {  // prefetch next tile (hidden under compute)
      kn0 = *(const bf16x8*)(kb + (size_t)(k0 + 64) * 3072);
      kn1 = *(const bf16x8*)(kb + (size_t)(k0 + 64) * 3072 + 8);
      vn0 = *(const bf16x8*)(vb + k0 + 64);
      vn1 = *(const bf16x8*)(vb + k0 + 64 + 8);
      mv = (tid < 64) ? mbase[k0 + 64 + tid] : 1;
    }
    __syncthreads();
    // S^T[k][q] = K · Q^T  (scale*log2e pre-folded into Q)
    f32x4 s[4];
#pragma unroll
    for (int kt = 0; kt < 4; ++kt) {
      bf16x8 kf0 = *(const bf16x8*)&Kl[KIX(kt * 16 + fr, fk)];
      bf16x8 kf1 = *(const bf16x8*)&Kl[KIX(kt * 16 + fr, fk + 32)];
      s[kt] = MFMA(kf0, qa0, zero4);
      s[kt] = MFMA(kf1, qa1, s[kt]);
    }
    // mask penalty: this lane's rows are k = kt*16 + g*4 + r
    const f32x4* mp4 = (const f32x4*)mpen;
#pragma unroll
    for (int kt = 0; kt < 4; ++kt) {
      f32x4 pen = mp4[kt * 4 + g];
#pragma unroll
      for (int r = 0; r < 4; ++r) s[kt][r] += pen[r];
    }
    // softmax per q-column: in-lane max/sum over 16 + 2-step cross-lane
    float t = fmaxf(fmaxf(fmaxf(s[0][0], s[0][1]), fmaxf(s[0][2], s[0][3])),
                    fmaxf(fmaxf(s[1][0], s[1][1]), fmaxf(s[1][2], s[1][3])));
    t = fmaxf(t, fmaxf(fmaxf(fmaxf(s[2][0], s[2][1]), fmaxf(s[2][2], s[2][3])),
                       fmaxf(fmaxf(s[3][0], s[3][1]), fmaxf(s[3][2], s[3][3]))));
    t = fmaxf(t, __shfl_xor(t, 16));
    t = fmaxf(t, __shfl_xor(t, 32));
    float mn = fmaxf(m_r, t);
    float fac = exp2f(m_r - mn);
    m_r = mn;
    float su = 0.f;
#pragma unroll
    for (int kt = 0; kt < 4; ++kt)
#pragma unroll
      for (int r = 0; r < 4; ++r) {
        s[kt][r] = exp2f(s[kt][r] - mn);
        su += s[kt][r];
      }
    su += __shfl_xor(su, 16);
    su += __shfl_xor(su, 32);
    l_r = l_r * fac + su;
#pragma unroll
    for (int dt = 0; dt < 4; ++dt)
#pragma unroll
      for (int r = 0; r < 4; ++r) cacc[dt][r] *= fac;
    // pack P rows to bf16 pairs (RTNE via v_cvt_pk_bf16_f32)
    unsigned pk[4][2];
#pragma unroll
    for (int kt = 0; kt < 4; ++kt) {
      asm("v_cvt_pk_bf16_f32 %0, %1, %2" : "=v"(pk[kt][0]) : "v"(s[kt][0]), "v"(s[kt][1]));
      asm("v_cvt_pk_bf16_f32 %0, %1, %2" : "=v"(pk[kt][1]) : "v"(s[kt][2]), "v"(s[kt][3]));
    }
    // redistribute: D-layout (row k, col q) -> B-frag (row q, k=(lane>>4)*8+j)
    union { unsigned u[4]; bf16x8 v; } pb0, pb1;
    {
      unsigned a00 = __builtin_amdgcn_ds_bpermute(addrA, (int)pk[0][0]);
      unsigned a10 = __builtin_amdgcn_ds_bpermute(addrA, (int)pk[1][0]);
      unsigned a01 = __builtin_amdgcn_ds_bpermute(addrA, (int)pk[0][1]);
      unsigned a11 = __builtin_amdgcn_ds_bpermute(addrA, (int)pk[1][1]);
      unsigned b00 = __builtin_amdgcn_ds_bpermute(addrB, (int)pk[0][0]);
      unsigned b10 = __builtin_amdgcn_ds_bpermute(addrB, (int)pk[1][0]);
      unsigned b01 = __builtin_amdgcn_ds_bpermute(addrB, (int)pk[0][1]);
      unsigned b11 = __builtin_amdgcn_ds_bpermute(addrB, (int)pk[1][1]);
      pb0.u[0] = hi ? a10 : a00;
      pb0.u[1] = hi ? a11 : a01;
      pb0.u[2] = hi ? b10 : b00;
      pb0.u[3] = hi ? b11 : b01;
    }
    {
      unsigned a20 = __builtin_amdgcn_ds_bpermute(addrA, (int)pk[2][0]);
      unsigned a30 = __builtin_amdgcn_ds_bpermute(addrA, (int)pk[3][0]);
      unsigned a21 = __builtin_amdgcn_ds_bpermute(addrA, (int)pk[2][1]);
      unsigned a31 = __builtin_amdgcn_ds_bpermute(addrA, (int)pk[3][1]);
      unsigned b20 = __builtin_amdgcn_ds_bpermute(addrB, (int)pk[2][0]);
      unsigned b30 = __builtin_amdgcn_ds_bpermute(addrB, (int)pk[3][0]);
      unsigned b21 = __builtin_amdgcn_ds_bpermute(addrB, (int)pk[2][1]);
      unsigned b31 = __builtin_amdgcn_ds_bpermute(addrB, (int)pk[3][1]);
      pb1.u[0] = hi ? a30 : a20;
      pb1.u[1] = hi ? a31 : a21;
      pb1.u[2] = hi ? b30 : b20;
      pb1.u[3] = hi ? b31 : b21;
    }
    // O^T[d][q] += V^T · P   (col = q stays lane-local)
#pragma unroll
    for (int dt = 0; dt < 4; ++dt) {
      bf16x8 vf0 = *(const bf16x8*)&Vl[KIX(dt * 16 + fr, fk)];
      bf16x8 vf1 = *(const bf16x8*)&Vl[KIX(dt * 16 + fr, fk + 32)];
      cacc[dt] = MFMA(vf0, pb0.v, cacc[dt]);
      cacc[dt] = MFMA(vf1, pb1.v, cacc[dt]);
    }
  }
  float invl = 1.f / l_r;
  unsigned short* obase =
      ctx + ((size_t)(b * 2048 + q0 + wid * 16 + qi)) * 1024 + h * 64 + (g << 2);
#pragma unroll
  for (int dt = 0; dt < 4; ++dt) {
    float v0 = cacc[dt][0] * invl, v1 = cacc[dt][1] * invl;
    float v2 = cacc[dt][2] * invl, v3 = cacc[dt][3] * invl;
    unsigned o0, o1;
    asm("v_cvt_pk_bf16_f32 %0, %1, %2" : "=v"(o0) : "v"(v0), "v"(v1));
    asm("v_cvt_pk_bf16_f32 %0, %1, %2" : "=v"(o1) : "v"(v2), "v"(v3));
    unsigned long long uu = ((unsigned long long)o1 << 32) | (unsigned long long)o0;
    *(unsigned long long*)(obase + dt * 16) = uu;
  }
}

// ---------------- launch ----------------
extern "C" void kernel_launch(void* const* d_in, const int* in_sizes, int n_in, void* d_out,
                              int out_size, void* d_ws, size_t ws_size, hipStream_t stream) {
  const float* x = (const float*)d_in[0];
  const int* amask = (const int*)d_in[1];
  const float* ln1w = (const float*)d_in[2];
  const float* ln1b = (const float*)d_in[3];
  const float* Uq = (const float*)d_in[4];
  const float* Vq = (const float*)d_in[5];
  const float* bq = (const float*)d_in[6];
  const float* Uk = (const float*)d_in[7];
  const float* Vk = (const float*)d_in[8];
  const float* bk = (const float*)d_in[9];
  const float* Uv = (const float*)d_in[10];
  const float* Vv = (const float*)d_in[11];
  const float* bv = (const float*)d_in[12];
  const float* Wo = (const float*)d_in[13];
  const float* bo = (const float*)d_in[14];
  const float* ln2w = (const float*)d_in[15];
  const float* ln2b = (const float*)d_in[16];
  const float* Uwi = (const float*)d_in[17];
  const float* Vwi = (const float*)d_in[18];
  const float* bwi = (const float*)d_in[19];
  const float* Uwo = (const float*)d_in[20];
  const float* Vwo = (const float*)d_in[21];
  const float* bwo = (const float*)d_in[22];

  char* ws = (char*)d_ws;
  size_t off = 0;
  auto alloc = [&](size_t bytes) {
    void* p = ws + off;
    off += (bytes + 255) & ~(size_t)255;
    return p;
  };
  // layout (~150 MB). g (64MB) aliases [qkv+ctx]; vT (16MB) aliases x1 (both dead then).
  unsigned short* xn = (unsigned short*)alloc((size_t)8192 * 1024 * 2);   // also xn2
  unsigned short* Wqkv = (unsigned short*)alloc((size_t)3072 * 1024 * 2);
  float* bqkv = (float*)alloc(3072 * 4);
  unsigned short* Wob = (unsigned short*)alloc((size_t)1024 * 1024 * 2);
  unsigned short* Uwit = (unsigned short*)alloc((size_t)512 * 1024 * 2);
  unsigned short* Vwit = (unsigned short*)alloc((size_t)8192 * 512 * 2);
  unsigned short* Uwot = (unsigned short*)alloc((size_t)512 * 4096 * 2);
  unsigned short* Vwot = (unsigned short*)alloc((size_t)1024 * 512 * 2);
  unsigned short* qkv = (unsigned short*)alloc((size_t)8192 * 3072 * 2);
  unsigned short* ctx = (unsigned short*)alloc((size_t)8192 * 1024 * 2);
  float* x1 = (float*)alloc((size_t)8192 * 1024 * 4);
  unsigned short* hr = (unsigned short*)alloc((size_t)8192 * 512 * 2);
  unsigned short* gr = (unsigned short*)alloc((size_t)8192 * 512 * 2);
  unsigned short* g = qkv;                 // alias: 64MB over qkv+ctx (dead by FFN)
  unsigned short* xn2 = xn;                // alias: xn dead after QKV gemm
  unsigned short* vT = (unsigned short*)x1;  // alias: x1 written only after attn
  if (off > ws_size) return;               // fail clean instead of faulting
  (void)in_sizes; (void)n_in; (void)out_size;

  dim3 tb(32, 8);
  // weight prep (runs every call; deterministic)
  k_build_wqkv<<<12288, 256, 0, stream>>>(Uq, Vq, Uk, Vk, Uv, Vv, Wqkv);
  k_concat_bias<<<12, 256, 0, stream>>>(bq, bk, bv, bqkv);
  k_f2bf<<<4096, 256, 0, stream>>>(Wo, Wob, 1024 * 1024);
  k_transpose_bf16<<<dim3(512 / 32, 1024 / 32), tb, 0, stream>>>(Uwi, Uwit, 1024, 512);
  k_transpose_bf16<<<dim3(8192 / 32, 512 / 32), tb, 0, stream>>>(Vwi, Vwit, 512, 8192);
  k_transpose_bf16<<<dim3(512 / 32, 4096 / 32), tb, 0, stream>>>(Uwo, Uwot, 4096, 512);
  k_transpose_bf16<<<dim3(1024 / 32, 512 / 32), tb, 0, stream>>>(Vwo, Vwot, 512, 1024);

  // block
  k_layernorm<<<8192, 256, 0, stream>>>(x, ln1w, ln1b, xn);
  k_gemm<1><<<dim3(24, 64), 256, 0, stream>>>(xn, Wqkv, bqkv, nullptr, qkv, 3072, 1024);
  k_rope<<<32768, 256, 0, stream>>>(qkv);
  k_vtrans<<<dim3(32, 64), 256, 0, stream>>>(qkv, vT);
  k_attn<<<dim3(32, 64), 256, 0, stream>>>(qkv, vT, amask, ctx);
  k_gemm<2><<<dim3(8, 64), 256, 0, stream>>>(ctx, Wob, bo, x, x1, 1024, 1024);
  k_layernorm<<<8192, 256, 0, stream>>>(x1, ln2w, ln2b, xn2);
  k_gemm<0><<<dim3(4, 64), 256, 0, stream>>>(xn2, Uwit, nullptr, nullptr, hr, 512, 1024);
  k_gemm_geglu<<<dim3(32, 64), 256, 0, stream>>>(hr, Vwit, bwi, g);
  k_gemm<0><<<dim3(4, 64), 256, 0, stream>>>(g, Uwot, nullptr, nullptr, gr, 512, 4096);
  k_gemm<2><<<dim3(8, 64), 256, 0, stream>>>(gr, Vwot, bwo, x1, d_out, 1024, 512);
}

// Round 5
// 627.352 us; speedup vs baseline: 1.2893x; 1.1520x over previous
//
#include <hip/hip_runtime.h>
#include <cstdint>

#define DEV __device__ __forceinline__

typedef __attribute__((ext_vector_type(8))) short bf16x8;
typedef __attribute__((ext_vector_type(4))) float f32x4;

#define MFMA(a,b,c) __builtin_amdgcn_mfma_f32_16x16x32_bf16((a),(b),(c),0,0,0)

DEV unsigned short f2bf(float f) {
  union { float f; unsigned u; } v; v.f = f;
  unsigned r = v.u + 0x7fffu + ((v.u >> 16) & 1u);
  return (unsigned short)(r >> 16);
}
DEV float bf2f(unsigned short s) {
  union { unsigned u; float f; } v; v.u = ((unsigned)s) << 16; return v.f;
}

// async global->LDS, 16B per lane. LDS dest is wave-uniform base + lane*16.
DEV void gload16(const unsigned short* g, short* l) {
  __builtin_amdgcn_global_load_lds(
      (const __attribute__((address_space(1))) unsigned*)g,
      (__attribute__((address_space(3))) unsigned*)l, 16, 0, 0);
}

// ---------------- prep kernels ----------------

// Wqkv_t[c3][d] = sum_r U[h][d][r]*V[h][r][k],  c3 = proj*1024 + h*64 + k
__global__ void k_build_wqkv(const float* __restrict__ Uq, const float* __restrict__ Vq,
                             const float* __restrict__ Uk, const float* __restrict__ Vk,
                             const float* __restrict__ Uv, const float* __restrict__ Vv,
                             unsigned short* __restrict__ W) {
  int idx = blockIdx.x * 256 + threadIdx.x;       // [0, 3072*1024)
  int d = idx & 1023;
  int c3 = idx >> 10;
  int proj = c3 >> 10;
  int c = c3 & 1023;
  int h = c >> 6, k = c & 63;
  const float* U = (proj == 0) ? Uq : (proj == 1) ? Uk : Uv;
  const float* V = (proj == 0) ? Vq : (proj == 1) ? Vk : Vv;
  const float* Urow = U + ((size_t)h * 1024 + d) * 32;
  const float* Vcol = V + (size_t)h * 32 * 64 + k;
  float s = 0.f;
#pragma unroll
  for (int r = 0; r < 32; ++r) s += Urow[r] * Vcol[r * 64];
  W[(size_t)c3 * 1024 + d] = f2bf(s);
}

__global__ void k_concat_bias(const float* __restrict__ bq, const float* __restrict__ bk,
                              const float* __restrict__ bv, float* __restrict__ out) {
  int i = blockIdx.x * 256 + threadIdx.x;
  if (i < 1024) out[i] = bq[i];
  else if (i < 2048) out[i] = bk[i - 1024];
  else if (i < 3072) out[i] = bv[i - 2048];
}

__global__ void k_f2bf(const float* __restrict__ in, unsigned short* __restrict__ out, int n) {
  int i = blockIdx.x * 256 + threadIdx.x;
  if (i < n) out[i] = f2bf(in[i]);
}

// fp32 [R][C] -> bf16 [C][R]
__global__ void k_transpose_bf16(const float* __restrict__ in, unsigned short* __restrict__ out,
                                 int R, int C) {
  __shared__ float tile[32][33];
  int c0 = blockIdx.x * 32, r0 = blockIdx.y * 32;
  int tx = threadIdx.x, ty = threadIdx.y;
#pragma unroll
  for (int i = ty; i < 32; i += 8)
    tile[i][tx] = in[(size_t)(r0 + i) * C + c0 + tx];
  __syncthreads();
#pragma unroll
  for (int i = ty; i < 32; i += 8)
    out[(size_t)(c0 + i) * R + r0 + tx] = f2bf(tile[tx][i]);
}

// bf16 V slice of qkv [tok][3072] -> vT[bh][d=64][m=2048]
__global__ __launch_bounds__(256) void k_vtrans(const unsigned short* __restrict__ qkv,
                                                unsigned short* __restrict__ vT) {
  __shared__ short t[64][66];
  int bh = blockIdx.y, b = bh >> 4, h = bh & 15;
  int m0 = blockIdx.x << 6;
  int tid = threadIdx.x;
  int rr = tid >> 2, cc = (tid & 3) << 4;
  const unsigned short* src = qkv + ((size_t)(b * 2048 + m0 + rr)) * 3072 + 2048 + h * 64 + cc;
  *(bf16x8*)&t[rr][cc] = *(const bf16x8*)src;
  *(bf16x8*)&t[rr][cc + 8] = *(const bf16x8*)(src + 8);
  __syncthreads();
  unsigned short* dst = vT + ((size_t)bh * 64 + rr) * 2048 + m0 + cc;
  bf16x8 o0, o1;
#pragma unroll
  for (int j = 0; j < 8; ++j) o0[j] = t[cc + j][rr];
#pragma unroll
  for (int j = 0; j < 8; ++j) o1[j] = t[cc + 8 + j][rr];
  *(bf16x8*)dst = o0;
  *(bf16x8*)(dst + 8) = o1;
}

// ---------------- layernorm (row = 1024 fp32 -> bf16) ----------------
__global__ __launch_bounds__(256) void k_layernorm(const float* __restrict__ x,
                                                   const float* __restrict__ w,
                                                   const float* __restrict__ b,
                                                   unsigned short* __restrict__ out) {
  int row = blockIdx.x;
  int tid = threadIdx.x;
  int lane = tid & 63, wid = tid >> 6;
  const float4 v = ((const float4*)(x + (size_t)row * 1024))[tid];
  float s = v.x + v.y + v.z + v.w;
  float s2 = v.x * v.x + v.y * v.y + v.z * v.z + v.w * v.w;
#pragma unroll
  for (int o = 1; o < 64; o <<= 1) { s += __shfl_xor(s, o); s2 += __shfl_xor(s2, o); }
  __shared__ float as_[4], as2_[4];
  if (lane == 0) { as_[wid] = s; as2_[wid] = s2; }
  __syncthreads();
  s = as_[0] + as_[1] + as_[2] + as_[3];
  s2 = as2_[0] + as2_[1] + as2_[2] + as2_[3];
  float mean = s * (1.f / 1024.f);
  float var = s2 * (1.f / 1024.f) - mean * mean;
  float inv = rsqrtf(var + 1e-5f);
  const float4 wv = ((const float4*)w)[tid];
  const float4 bv = ((const float4*)b)[tid];
  union { unsigned short u[4]; unsigned long long ll; } o;
  o.u[0] = f2bf((v.x - mean) * inv * wv.x + bv.x);
  o.u[1] = f2bf((v.y - mean) * inv * wv.y + bv.y);
  o.u[2] = f2bf((v.z - mean) * inv * wv.z + bv.z);
  o.u[3] = f2bf((v.w - mean) * inv * wv.w + bv.w);
  ((unsigned long long*)(out + (size_t)row * 1024))[tid] = o.ll;
}

// ---------------- GEMM: C[8192 x N] = A[8192 x K](bf16) * Bt[N x K]^T ----------------
// m97 structure: linear [128][32] LDS tiles filled by global_load_lds width-16.
// Wave w stages rows w*32..w*32+31 (two 16-row issues; lane l -> row l>>2, col (l&3)*8).
// EPI 0: bf16 out;  1: bf16 out + bias;  2: f32 out + bias + resid
template <int EPI>
__global__ __launch_bounds__(256, 2) void k_gemm(const unsigned short* __restrict__ A,
                                                 const unsigned short* __restrict__ Bt,
                                                 const float* __restrict__ bias,
                                                 const float* __restrict__ resid,
                                                 void* __restrict__ outp, int N, int K) {
  __shared__ short Al[128 * 32];
  __shared__ short Bl[128 * 32];
  int tid = threadIdx.x, lane = tid & 63, wid = tid >> 6;
  int wr = wid >> 1, wc = wid & 1;
  size_t row0 = (size_t)blockIdx.y * 128;
  int col0 = blockIdx.x * 128;
  int arow = lane >> 2, acol = (lane & 3) << 3;
  const unsigned short* Ag = A + (row0 + wid * 32 + arow) * K + acol;
  const unsigned short* Bg = Bt + ((size_t)(col0 + wid * 32 + arow)) * K + acol;
  short* Ald = Al + wid * 1024;
  short* Bld = Bl + wid * 1024;
  f32x4 acc[4][4] = {};
  int fr = lane & 15, fk = (lane >> 4) << 3;
  for (int k0 = 0; k0 < K; k0 += 32) {
    __syncthreads();  // prior tile's LDS reads done
    gload16(Ag + k0, Ald);
    gload16(Ag + (size_t)16 * K + k0, Ald + 512);
    gload16(Bg + k0, Bld);
    gload16(Bg + (size_t)16 * K + k0, Bld + 512);
    __syncthreads();  // barrier drains vmcnt -> tile ready
    bf16x8 af[4], bfr[4];
#pragma unroll
    for (int i = 0; i < 4; ++i) {
      af[i] = *(const bf16x8*)&Al[(wr * 64 + i * 16 + fr) * 32 + fk];
      bfr[i] = *(const bf16x8*)&Bl[(wc * 64 + i * 16 + fr) * 32 + fk];
    }
#pragma unroll
    for (int i = 0; i < 4; ++i)
#pragma unroll
      for (int j = 0; j < 4; ++j) acc[i][j] = MFMA(af[i], bfr[j], acc[i][j]);
  }
  int cr = (lane >> 4) << 2, cc = lane & 15;
#pragma unroll
  for (int j = 0; j < 4; ++j) {
    int col = col0 + wc * 64 + j * 16 + cc;
    float bb = (EPI >= 1) ? bias[col] : 0.f;
#pragma unroll
    for (int i = 0; i < 4; ++i) {
#pragma unroll
      for (int r = 0; r < 4; ++r) {
        size_t row = row0 + wr * 64 + i * 16 + cr + r;
        float v = acc[i][j][r] + bb;
        if (EPI == 2)
          ((float*)outp)[row * N + col] = v + resid[row * N + col];
        else
          ((unsigned short*)outp)[row * N + col] = f2bf(v);
      }
    }
  }
}

// ---------------- GEMM + GEGLU: g = gelu_tanh(h1) * h2 ----------------
// A = hr [8192 x 512], Bt = V_wi_t [8192 x 512] (rows: out-col), out g [8192 x 4096] bf16
__global__ __launch_bounds__(256, 2) void k_gemm_geglu(const unsigned short* __restrict__ A,
                                                       const unsigned short* __restrict__ Bt,
                                                       const float* __restrict__ bias,
                                                       unsigned short* __restrict__ out) {
  __shared__ short Al[128 * 32];
  __shared__ short B1l[128 * 32];
  __shared__ short B2l[128 * 32];
  const int K = 512;
  int tid = threadIdx.x, lane = tid & 63, wid = tid >> 6;
  int wr = wid >> 1, wc = wid & 1;
  size_t row0 = (size_t)blockIdx.y * 128;
  int col0 = blockIdx.x * 128;
  int arow = lane >> 2, acol = (lane & 3) << 3;
  const unsigned short* Ag = A + (row0 + wid * 32 + arow) * K + acol;
  const unsigned short* B1g = Bt + ((size_t)(col0 + wid * 32 + arow)) * K + acol;
  const unsigned short* B2g = Bt + ((size_t)(col0 + 4096 + wid * 32 + arow)) * K + acol;
  short* Ald = Al + wid * 1024;
  short* B1d = B1l + wid * 1024;
  short* B2d = B2l + wid * 1024;
  f32x4 acc1[4][4] = {}, acc2[4][4] = {};
  int fr = lane & 15, fk = (lane >> 4) << 3;
  for (int k0 = 0; k0 < K; k0 += 32) {
    __syncthreads();
    gload16(Ag + k0, Ald);
    gload16(Ag + (size_t)16 * K + k0, Ald + 512);
    gload16(B1g + k0, B1d);
    gload16(B1g + (size_t)16 * K + k0, B1d + 512);
    gload16(B2g + k0, B2d);
    gload16(B2g + (size_t)16 * K + k0, B2d + 512);
    __syncthreads();
    bf16x8 af[4], b1f[4], b2f[4];
#pragma unroll
    for (int i = 0; i < 4; ++i) {
      af[i] = *(const bf16x8*)&Al[(wr * 64 + i * 16 + fr) * 32 + fk];
      b1f[i] = *(const bf16x8*)&B1l[(wc * 64 + i * 16 + fr) * 32 + fk];
      b2f[i] = *(const bf16x8*)&B2l[(wc * 64 + i * 16 + fr) * 32 + fk];
    }
#pragma unroll
    for (int i = 0; i < 4; ++i)
#pragma unroll
      for (int j = 0; j < 4; ++j) {
        acc1[i][j] = MFMA(af[i], b1f[j], acc1[i][j]);
        acc2[i][j] = MFMA(af[i], b2f[j], acc2[i][j]);
      }
  }
  int cr = (lane >> 4) << 2, cc = lane & 15;
#pragma unroll
  for (int j = 0; j < 4; ++j) {
    int col = col0 + wc * 64 + j * 16 + cc;
    float bb1 = bias[col], bb2 = bias[col + 4096];
#pragma unroll
    for (int i = 0; i < 4; ++i) {
#pragma unroll
      for (int r = 0; r < 4; ++r) {
        size_t row = row0 + wr * 64 + i * 16 + cr + r;
        float h1 = acc1[i][j][r] + bb1;
        float h2 = acc2[i][j][r] + bb2;
        float u = 0.7978845608028654f * (h1 + 0.044715f * h1 * h1 * h1);
        float e = __expf(2.f * u);
        float th = 1.f - 2.f / (e + 1.f);
        float gv = 0.5f * h1 * (1.f + th) * h2;
        out[row * 4096 + col] = f2bf(gv);
      }
    }
  }
}

// ---------------- RoPE in-place on qkv ----------------
// Q scale folds 1/sqrt(64) AND log2(e) (softmax uses exp2).
__global__ void k_rope(unsigned short* __restrict__ qkv) {
  int idx = blockIdx.x * 256 + threadIdx.x;  // [0, 8192*1024)
  int tok = idx >> 10;
  int rem = idx & 1023;
  int isk = rem >> 9;
  int h = (rem >> 5) & 15;
  int i = rem & 31;
  int m = tok & 2047;
  size_t base = (size_t)tok * 3072 + (size_t)isk * 1024 + h * 64 + i;
  float x1 = bf2f(qkv[base]);
  float x2 = bf2f(qkv[base + 32]);
  float ang = (float)m * __expf((float)i * -0.28782313662425575f);  // ln(10000)/32
  float sn, cs;
  __sincosf(ang, &sn, &cs);
  float sc = isk ? 1.f : 0.18033688011112042f;  // 0.125 * log2(e)
  qkv[base] = f2bf((x1 * cs - x2 * sn) * sc);
  qkv[base + 32] = f2bf((x2 * cs + x1 * sn) * sc);
}

// ---------------- flash attention (swapped-operand, in-register softmax) ----------------
// grid (M/64, B*H); 4 waves x 16 q rows. S^T = MFMA(K,Q): col=lane&15=q, so each
// q-column's k-values are in-lane -> softmax = in-lane reduce + 2 shfl_xor.
// PV as O^T = MFMA(V^T, P); P redistributed D-layout->B-layout via cvt_pk + bpermute.
#define KIX(r, c) ((r) * 64 + ((c) ^ (((r) & 7) << 3)))

__global__ __launch_bounds__(256, 4) void k_attn(const unsigned short* __restrict__ qkv,
                                                 const unsigned short* __restrict__ vT,
                                                 const int* __restrict__ mask,
                                                 unsigned short* __restrict__ ctx) {
  __shared__ short Kl[64 * 64];
  __shared__ short Vl[64 * 64];
  __shared__ float mpen[64];
  int bh = blockIdx.y, b = bh >> 4, h = bh & 15;
  int q0 = blockIdx.x << 6;
  int tid = threadIdx.x, lane = tid & 63, wid = tid >> 6;
  int fr = lane & 15, fk = (lane >> 4) << 3;
  int g = lane >> 4, qi = lane & 15;
  const unsigned short* qbase =
      qkv + ((size_t)(b * 2048 + q0 + wid * 16 + fr)) * 3072 + h * 64;
  bf16x8 qa0 = *(const bf16x8*)(qbase + fk);
  bf16x8 qa1 = *(const bf16x8*)(qbase + 32 + fk);
  float m_r = -1e30f, l_r = 0.f;
  f32x4 cacc[4] = {};
  int srow = tid >> 2;
  int sc = (tid & 3) << 4;
  const unsigned short* kb =
      qkv + ((size_t)(b * 2048 + srow)) * 3072 + 1024 + h * 64 + sc;
  const unsigned short* vb = vT + ((size_t)bh * 64 + srow) * 2048 + sc;
  const int* mbase = mask + b * 2048;
  const f32x4 zero4 = {0.f, 0.f, 0.f, 0.f};
  // bpermute byte-addresses for P redistribution (hoisted)
  int addrA = (((g & 1) << 5) + qi) << 2;  // src lane (g&1)*32 + q
  int addrB = addrA + 64;                  // +16 lanes
  bool hi = ((g >> 1) & 1) != 0;
  // prefetch tile 0
  bf16x8 kn0 = *(const bf16x8*)kb;
  bf16x8 kn1 = *(const bf16x8*)(kb + 8);
  bf16x8 vn0 = *(const bf16x8*)vb;
  bf16x8 vn1 = *(const bf16x8*)(vb + 8);
  int mv = (tid < 64) ? mbase[tid] : 1;
  for (int k0 = 0; k0 < 2048; k0 += 64) {
    __syncthreads();  // prior tile's LDS reads drained
    *(bf16x8*)&Kl[KIX(srow, sc)] = kn0;
    *(bf16x8*)&Kl[KIX(srow, sc + 8)] = kn1;
    *(bf16x8*)&Vl[KIX(srow, sc)] = vn0;
    *(bf16x8*)&Vl[KIX(srow, sc + 8)] = vn1;
    if (tid < 64) mpen[tid] = (mv == 0) ? -1e30f : 0.f;
    if (k0 + 64 < 2048) {  // prefetch next tile (hidden under compute)
      kn0 = *(const bf16x8*)(kb + (size_t)(k0 + 64) * 3072);
      kn1 = *(const bf16x8*)(kb + (size_t)(k0 + 64) * 3072 + 8);
      vn0 = *(const bf16x8*)(vb + k0 + 64);
      vn1 = *(const bf16x8*)(vb + k0 + 64 + 8);
      mv = (tid < 64) ? mbase[k0 + 64 + tid] : 1;
    }
    __syncthreads();
    // S^T[k][q] = K · Q^T  (scale*log2e pre-folded into Q)
    f32x4 s[4];
#pragma unroll
    for (int kt = 0; kt < 4; ++kt) {
      bf16x8 kf0 = *(const bf16x8*)&Kl[KIX(kt * 16 + fr, fk)];
      bf16x8 kf1 = *(const bf16x8*)&Kl[KIX(kt * 16 + fr, fk + 32)];
      s[kt] = MFMA(kf0, qa0, zero4);
      s[kt] = MFMA(kf1, qa1, s[kt]);
    }
    // mask penalty: this lane's rows are k = kt*16 + g*4 + r
    const f32x4* mp4 = (const f32x4*)mpen;
#pragma unroll
    for (int kt = 0; kt < 4; ++kt) {
      f32x4 pen = mp4[kt * 4 + g];
#pragma unroll
      for (int r = 0; r < 4; ++r) s[kt][r] += pen[r];
    }
    // softmax per q-column: in-lane max/sum over 16 + 2-step cross-lane
    float t = fmaxf(fmaxf(fmaxf(s[0][0], s[0][1]), fmaxf(s[0][2], s[0][3])),
                    fmaxf(fmaxf(s[1][0], s[1][1]), fmaxf(s[1][2], s[1][3])));
    t = fmaxf(t, fmaxf(fmaxf(fmaxf(s[2][0], s[2][1]), fmaxf(s[2][2], s[2][3])),
                       fmaxf(fmaxf(s[3][0], s[3][1]), fmaxf(s[3][2], s[3][3]))));
    t = fmaxf(t, __shfl_xor(t, 16));
    t = fmaxf(t, __shfl_xor(t, 32));
    float mn = fmaxf(m_r, t);
    float fac = exp2f(m_r - mn);
    m_r = mn;
    float su = 0.f;
#pragma unroll
    for (int kt = 0; kt < 4; ++kt)
#pragma unroll
      for (int r = 0; r < 4; ++r) {
        s[kt][r] = exp2f(s[kt][r] - mn);
        su += s[kt][r];
      }
    su += __shfl_xor(su, 16);
    su += __shfl_xor(su, 32);
    l_r = l_r * fac + su;
#pragma unroll
    for (int dt = 0; dt < 4; ++dt)
#pragma unroll
      for (int r = 0; r < 4; ++r) cacc[dt][r] *= fac;
    // pack P rows to bf16 pairs (RTNE via v_cvt_pk_bf16_f32)
    unsigned pk[4][2];
#pragma unroll
    for (int kt = 0; kt < 4; ++kt) {
      asm("v_cvt_pk_bf16_f32 %0, %1, %2" : "=v"(pk[kt][0]) : "v"(s[kt][0]), "v"(s[kt][1]));
      asm("v_cvt_pk_bf16_f32 %0, %1, %2" : "=v"(pk[kt][1]) : "v"(s[kt][2]), "v"(s[kt][3]));
    }
    // redistribute: D-layout (row k, col q) -> B-frag (row q, k=(lane>>4)*8+j)
    union { unsigned u[4]; bf16x8 v; } pb0, pb1;
    {
      unsigned a00 = __builtin_amdgcn_ds_bpermute(addrA, (int)pk[0][0]);
      unsigned a10 = __builtin_amdgcn_ds_bpermute(addrA, (int)pk[1][0]);
      unsigned a01 = __builtin_amdgcn_ds_bpermute(addrA, (int)pk[0][1]);
      unsigned a11 = __builtin_amdgcn_ds_bpermute(addrA, (int)pk[1][1]);
      unsigned b00 = __builtin_amdgcn_ds_bpermute(addrB, (int)pk[0][0]);
      unsigned b10 = __builtin_amdgcn_ds_bpermute(addrB, (int)pk[1][0]);
      unsigned b01 = __builtin_amdgcn_ds_bpermute(addrB, (int)pk[0][1]);
      unsigned b11 = __builtin_amdgcn_ds_bpermute(addrB, (int)pk[1][1]);
      pb0.u[0] = hi ? a10 : a00;
      pb0.u[1] = hi ? a11 : a01;
      pb0.u[2] = hi ? b10 : b00;
      pb0.u[3] = hi ? b11 : b01;
    }
    {
      unsigned a20 = __builtin_amdgcn_ds_bpermute(addrA, (int)pk[2][0]);
      unsigned a30 = __builtin_amdgcn_ds_bpermute(addrA, (int)pk[3][0]);
      unsigned a21 = __builtin_amdgcn_ds_bpermute(addrA, (int)pk[2][1]);
      unsigned a31 = __builtin_amdgcn_ds_bpermute(addrA, (int)pk[3][1]);
      unsigned b20 = __builtin_amdgcn_ds_bpermute(addrB, (int)pk[2][0]);
      unsigned b30 = __builtin_amdgcn_ds_bpermute(addrB, (int)pk[3][0]);
      unsigned b21 = __builtin_amdgcn_ds_bpermute(addrB, (int)pk[2][1]);
      unsigned b31 = __builtin_amdgcn_ds_bpermute(addrB, (int)pk[3][1]);
      pb1.u[0] = hi ? a30 : a20;
      pb1.u[1] = hi ? a31 : a21;
      pb1.u[2] = hi ? b30 : b20;
      pb1.u[3] = hi ? b31 : b21;
    }
    // O^T[d][q] += V^T · P   (col = q stays lane-local)
#pragma unroll
    for (int dt = 0; dt < 4; ++dt) {
      bf16x8 vf0 = *(const bf16x8*)&Vl[KIX(dt * 16 + fr, fk)];
      bf16x8 vf1 = *(const bf16x8*)&Vl[KIX(dt * 16 + fr, fk + 32)];
      cacc[dt] = MFMA(vf0, pb0.v, cacc[dt]);
      cacc[dt] = MFMA(vf1, pb1.v, cacc[dt]);
    }
  }
  float invl = 1.f / l_r;
  unsigned short* obase =
      ctx + ((size_t)(b * 2048 + q0 + wid * 16 + qi)) * 1024 + h * 64 + (g << 2);
#pragma unroll
  for (int dt = 0; dt < 4; ++dt) {
    float v0 = cacc[dt][0] * invl, v1 = cacc[dt][1] * invl;
    float v2 = cacc[dt][2] * invl, v3 = cacc[dt][3] * invl;
    unsigned o0, o1;
    asm("v_cvt_pk_bf16_f32 %0, %1, %2" : "=v"(o0) : "v"(v0), "v"(v1));
    asm("v_cvt_pk_bf16_f32 %0, %1, %2" : "=v"(o1) : "v"(v2), "v"(v3));
    unsigned long long uu = ((unsigned long long)o1 << 32) | (unsigned long long)o0;
    *(unsigned long long*)(obase + dt * 16) = uu;
  }
}

// ---------------- launch ----------------
extern "C" void kernel_launch(void* const* d_in, const int* in_sizes, int n_in, void* d_out,
                              int out_size, void* d_ws, size_t ws_size, hipStream_t stream) {
  const float* x = (const float*)d_in[0];
  const int* amask = (const int*)d_in[1];
  const float* ln1w = (const float*)d_in[2];
  const float* ln1b = (const float*)d_in[3];
  const float* Uq = (const float*)d_in[4];
  const float* Vq = (const float*)d_in[5];
  const float* bq = (const float*)d_in[6];
  const float* Uk = (const float*)d_in[7];
  const float* Vk = (const float*)d_in[8];
  const float* bk = (const float*)d_in[9];
  const float* Uv = (const float*)d_in[10];
  const float* Vv = (const float*)d_in[11];
  const float* bv = (const float*)d_in[12];
  const float* Wo = (const float*)d_in[13];
  const float* bo = (const float*)d_in[14];
  const float* ln2w = (const float*)d_in[15];
  const float* ln2b = (const float*)d_in[16];
  const float* Uwi = (const float*)d_in[17];
  const float* Vwi = (const float*)d_in[18];
  const float* bwi = (const float*)d_in[19];
  const float* Uwo = (const float*)d_in[20];
  const float* Vwo = (const float*)d_in[21];
  const float* bwo = (const float*)d_in[22];

  char* ws = (char*)d_ws;
  size_t off = 0;
  auto alloc = [&](size_t bytes) {
    void* p = ws + off;
    off += (bytes + 255) & ~(size_t)255;
    return p;
  };
  // layout (~150 MB). g (64MB) aliases [qkv+ctx]; vT (16MB) aliases x1 (both dead then).
  unsigned short* xn = (unsigned short*)alloc((size_t)8192 * 1024 * 2);   // also xn2
  unsigned short* Wqkv = (unsigned short*)alloc((size_t)3072 * 1024 * 2);
  float* bqkv = (float*)alloc(3072 * 4);
  unsigned short* Wob = (unsigned short*)alloc((size_t)1024 * 1024 * 2);
  unsigned short* Uwit = (unsigned short*)alloc((size_t)512 * 1024 * 2);
  unsigned short* Vwit = (unsigned short*)alloc((size_t)8192 * 512 * 2);
  unsigned short* Uwot = (unsigned short*)alloc((size_t)512 * 4096 * 2);
  unsigned short* Vwot = (unsigned short*)alloc((size_t)1024 * 512 * 2);
  unsigned short* qkv = (unsigned short*)alloc((size_t)8192 * 3072 * 2);
  unsigned short* ctx = (unsigned short*)alloc((size_t)8192 * 1024 * 2);
  float* x1 = (float*)alloc((size_t)8192 * 1024 * 4);
  unsigned short* hr = (unsigned short*)alloc((size_t)8192 * 512 * 2);
  unsigned short* gr = (unsigned short*)alloc((size_t)8192 * 512 * 2);
  unsigned short* g = qkv;                 // alias: 64MB over qkv+ctx (dead by FFN)
  unsigned short* xn2 = xn;                // alias: xn dead after QKV gemm
  unsigned short* vT = (unsigned short*)x1;  // alias: x1 written only after attn
  if (off > ws_size) return;               // fail clean instead of faulting
  (void)in_sizes; (void)n_in; (void)out_size;

  dim3 tb(32, 8);
  // weight prep (runs every call; deterministic)
  k_build_wqkv<<<12288, 256, 0, stream>>>(Uq, Vq, Uk, Vk, Uv, Vv, Wqkv);
  k_concat_bias<<<12, 256, 0, stream>>>(bq, bk, bv, bqkv);
  k_f2bf<<<4096, 256, 0, stream>>>(Wo, Wob, 1024 * 1024);
  k_transpose_bf16<<<dim3(512 / 32, 1024 / 32), tb, 0, stream>>>(Uwi, Uwit, 1024, 512);
  k_transpose_bf16<<<dim3(8192 / 32, 512 / 32), tb, 0, stream>>>(Vwi, Vwit, 512, 8192);
  k_transpose_bf16<<<dim3(512 / 32, 4096 / 32), tb, 0, stream>>>(Uwo, Uwot, 4096, 512);
  k_transpose_bf16<<<dim3(1024 / 32, 512 / 32), tb, 0, stream>>>(Vwo, Vwot, 512, 1024);

  // block
  k_layernorm<<<8192, 256, 0, stream>>>(x, ln1w, ln1b, xn);
  k_gemm<1><<<dim3(24, 64), 256, 0, stream>>>(xn, Wqkv, bqkv, nullptr, qkv, 3072, 1024);
  k_rope<<<32768, 256, 0, stream>>>(qkv);
  k_vtrans<<<dim3(32, 64), 256, 0, stream>>>(qkv, vT);
  k_attn<<<dim3(32, 64), 256, 0, stream>>>(qkv, vT, amask, ctx);
  k_gemm<2><<<dim3(8, 64), 256, 0, stream>>>(ctx, Wob, bo, x, x1, 1024, 1024);
  k_layernorm<<<8192, 256, 0, stream>>>(x1, ln2w, ln2b, xn2);
  k_gemm<0><<<dim3(4, 64), 256, 0, stream>>>(xn2, Uwit, nullptr, nullptr, hr, 512, 1024);
  k_gemm_geglu<<<dim3(32, 64), 256, 0, stream>>>(hr, Vwit, bwi, g);
  k_gemm<0><<<dim3(4, 64), 256, 0, stream>>>(g, Uwot, nullptr, nullptr, gr, 512, 4096);
  k_gemm<2><<<dim3(8, 64), 256, 0, stream>>>(gr, Vwot, bwo, x1, d_out, 1024, 512);
}

// Round 6
// 603.089 us; speedup vs baseline: 1.3412x; 1.0402x over previous
//
#include <hip/hip_runtime.h>
#include <cstdint>

#define DEV __device__ __forceinline__

typedef __attribute__((ext_vector_type(8))) short bf16x8;
typedef __attribute__((ext_vector_type(4))) float f32x4;

#define MFMA(a,b,c) __builtin_amdgcn_mfma_f32_16x16x32_bf16((a),(b),(c),0,0,0)

DEV unsigned short f2bf(float f) {
  union { float f; unsigned u; } v; v.f = f;
  unsigned r = v.u + 0x7fffu + ((v.u >> 16) & 1u);
  return (unsigned short)(r >> 16);
}
DEV float bf2f(unsigned short s) {
  union { unsigned u; float f; } v; v.u = ((unsigned)s) << 16; return v.f;
}
DEV float max3f(float a, float b, float c) { return fmaxf(fmaxf(a, b), c); }

// async global->LDS, 16B per lane. LDS dest is wave-uniform base + lane*16.
DEV void gload16(const unsigned short* g, short* l) {
  __builtin_amdgcn_global_load_lds(
      (const __attribute__((address_space(1))) unsigned*)g,
      (__attribute__((address_space(3))) unsigned*)l, 16, 0, 0);
}

// ---------------- prep kernels ----------------

// Wqkv_t[c3][d] = sum_r U[h][d][r]*V[h][r][k],  c3 = proj*1024 + h*64 + k
__global__ void k_build_wqkv(const float* __restrict__ Uq, const float* __restrict__ Vq,
                             const float* __restrict__ Uk, const float* __restrict__ Vk,
                             const float* __restrict__ Uv, const float* __restrict__ Vv,
                             unsigned short* __restrict__ W) {
  int idx = blockIdx.x * 256 + threadIdx.x;       // [0, 3072*1024)
  int d = idx & 1023;
  int c3 = idx >> 10;
  int proj = c3 >> 10;
  int c = c3 & 1023;
  int h = c >> 6, k = c & 63;
  const float* U = (proj == 0) ? Uq : (proj == 1) ? Uk : Uv;
  const float* V = (proj == 0) ? Vq : (proj == 1) ? Vk : Vv;
  const float* Urow = U + ((size_t)h * 1024 + d) * 32;
  const float* Vcol = V + (size_t)h * 32 * 64 + k;
  float s = 0.f;
#pragma unroll
  for (int r = 0; r < 32; ++r) s += Urow[r] * Vcol[r * 64];
  W[(size_t)c3 * 1024 + d] = f2bf(s);
}

__global__ void k_concat_bias(const float* __restrict__ bq, const float* __restrict__ bk,
                              const float* __restrict__ bv, float* __restrict__ out) {
  int i = blockIdx.x * 256 + threadIdx.x;
  if (i < 1024) out[i] = bq[i];
  else if (i < 2048) out[i] = bk[i - 1024];
  else if (i < 3072) out[i] = bv[i - 2048];
}

__global__ void k_f2bf(const float* __restrict__ in, unsigned short* __restrict__ out, int n) {
  int i = blockIdx.x * 256 + threadIdx.x;
  if (i < n) out[i] = f2bf(in[i]);
}

// fp32 [R][C] -> bf16 [C][R]
__global__ void k_transpose_bf16(const float* __restrict__ in, unsigned short* __restrict__ out,
                                 int R, int C) {
  __shared__ float tile[32][33];
  int c0 = blockIdx.x * 32, r0 = blockIdx.y * 32;
  int tx = threadIdx.x, ty = threadIdx.y;
#pragma unroll
  for (int i = ty; i < 32; i += 8)
    tile[i][tx] = in[(size_t)(r0 + i) * C + c0 + tx];
  __syncthreads();
#pragma unroll
  for (int i = ty; i < 32; i += 8)
    out[(size_t)(c0 + i) * R + r0 + tx] = f2bf(tile[tx][i]);
}

// bf16 V slice of qkv [tok][3072] -> vT[bh][d=64][m=2048]
__global__ __launch_bounds__(256) void k_vtrans(const unsigned short* __restrict__ qkv,
                                                unsigned short* __restrict__ vT) {
  __shared__ short t[64][66];
  int bh = blockIdx.y, b = bh >> 4, h = bh & 15;
  int m0 = blockIdx.x << 6;
  int tid = threadIdx.x;
  int rr = tid >> 2, cc = (tid & 3) << 4;
  const unsigned short* src = qkv + ((size_t)(b * 2048 + m0 + rr)) * 3072 + 2048 + h * 64 + cc;
  *(bf16x8*)&t[rr][cc] = *(const bf16x8*)src;
  *(bf16x8*)&t[rr][cc + 8] = *(const bf16x8*)(src + 8);
  __syncthreads();
  unsigned short* dst = vT + ((size_t)bh * 64 + rr) * 2048 + m0 + cc;
  bf16x8 o0, o1;
#pragma unroll
  for (int j = 0; j < 8; ++j) o0[j] = t[cc + j][rr];
#pragma unroll
  for (int j = 0; j < 8; ++j) o1[j] = t[cc + 8 + j][rr];
  *(bf16x8*)dst = o0;
  *(bf16x8*)(dst + 8) = o1;
}

// ---------------- layernorm (row = 1024 fp32 -> bf16) ----------------
__global__ __launch_bounds__(256) void k_layernorm(const float* __restrict__ x,
                                                   const float* __restrict__ w,
                                                   const float* __restrict__ b,
                                                   unsigned short* __restrict__ out) {
  int row = blockIdx.x;
  int tid = threadIdx.x;
  int lane = tid & 63, wid = tid >> 6;
  const float4 v = ((const float4*)(x + (size_t)row * 1024))[tid];
  float s = v.x + v.y + v.z + v.w;
  float s2 = v.x * v.x + v.y * v.y + v.z * v.z + v.w * v.w;
#pragma unroll
  for (int o = 1; o < 64; o <<= 1) { s += __shfl_xor(s, o); s2 += __shfl_xor(s2, o); }
  __shared__ float as_[4], as2_[4];
  if (lane == 0) { as_[wid] = s; as2_[wid] = s2; }
  __syncthreads();
  s = as_[0] + as_[1] + as_[2] + as_[3];
  s2 = as2_[0] + as2_[1] + as2_[2] + as2_[3];
  float mean = s * (1.f / 1024.f);
  float var = s2 * (1.f / 1024.f) - mean * mean;
  float inv = rsqrtf(var + 1e-5f);
  const float4 wv = ((const float4*)w)[tid];
  const float4 bv = ((const float4*)b)[tid];
  union { unsigned short u[4]; unsigned long long ll; } o;
  o.u[0] = f2bf((v.x - mean) * inv * wv.x + bv.x);
  o.u[1] = f2bf((v.y - mean) * inv * wv.y + bv.y);
  o.u[2] = f2bf((v.z - mean) * inv * wv.z + bv.z);
  o.u[3] = f2bf((v.w - mean) * inv * wv.w + bv.w);
  ((unsigned long long*)(out + (size_t)row * 1024))[tid] = o.ll;
}

// ---------------- GEMM: C[8192 x N] = A[8192 x K](bf16) * Bt[N x K]^T ----------------
// m97 structure: linear [128][32] LDS tiles filled by global_load_lds width-16.
// EPI 0: bf16 out;  1: bf16 out + bias;  2: f32 out + bias + resid
template <int EPI>
__global__ __launch_bounds__(256, 2) void k_gemm(const unsigned short* __restrict__ A,
                                                 const unsigned short* __restrict__ Bt,
                                                 const float* __restrict__ bias,
                                                 const float* __restrict__ resid,
                                                 void* __restrict__ outp, int N, int K) {
  __shared__ short Al[128 * 32];
  __shared__ short Bl[128 * 32];
  int tid = threadIdx.x, lane = tid & 63, wid = tid >> 6;
  int wr = wid >> 1, wc = wid & 1;
  size_t row0 = (size_t)blockIdx.y * 128;
  int col0 = blockIdx.x * 128;
  int arow = lane >> 2, acol = (lane & 3) << 3;
  const unsigned short* Ag = A + (row0 + wid * 32 + arow) * K + acol;
  const unsigned short* Bg = Bt + ((size_t)(col0 + wid * 32 + arow)) * K + acol;
  short* Ald = Al + wid * 1024;
  short* Bld = Bl + wid * 1024;
  f32x4 acc[4][4] = {};
  int fr = lane & 15, fk = (lane >> 4) << 3;
  for (int k0 = 0; k0 < K; k0 += 32) {
    __syncthreads();  // prior tile's LDS reads done
    gload16(Ag + k0, Ald);
    gload16(Ag + (size_t)16 * K + k0, Ald + 512);
    gload16(Bg + k0, Bld);
    gload16(Bg + (size_t)16 * K + k0, Bld + 512);
    __syncthreads();  // barrier drains vmcnt -> tile ready
    bf16x8 af[4], bfr[4];
#pragma unroll
    for (int i = 0; i < 4; ++i) {
      af[i] = *(const bf16x8*)&Al[(wr * 64 + i * 16 + fr) * 32 + fk];
      bfr[i] = *(const bf16x8*)&Bl[(wc * 64 + i * 16 + fr) * 32 + fk];
    }
#pragma unroll
    for (int i = 0; i < 4; ++i)
#pragma unroll
      for (int j = 0; j < 4; ++j) acc[i][j] = MFMA(af[i], bfr[j], acc[i][j]);
  }
  int cr = (lane >> 4) << 2, cc = lane & 15;
#pragma unroll
  for (int j = 0; j < 4; ++j) {
    int col = col0 + wc * 64 + j * 16 + cc;
    float bb = (EPI >= 1) ? bias[col] : 0.f;
#pragma unroll
    for (int i = 0; i < 4; ++i) {
#pragma unroll
      for (int r = 0; r < 4; ++r) {
        size_t row = row0 + wr * 64 + i * 16 + cr + r;
        float v = acc[i][j][r] + bb;
        if (EPI == 2)
          ((float*)outp)[row * N + col] = v + resid[row * N + col];
        else
          ((unsigned short*)outp)[row * N + col] = f2bf(v);
      }
    }
  }
}

// ---------------- GEMM + GEGLU: g = gelu_tanh(h1) * h2 ----------------
__global__ __launch_bounds__(256, 2) void k_gemm_geglu(const unsigned short* __restrict__ A,
                                                       const unsigned short* __restrict__ Bt,
                                                       const float* __restrict__ bias,
                                                       unsigned short* __restrict__ out) {
  __shared__ short Al[128 * 32];
  __shared__ short B1l[128 * 32];
  __shared__ short B2l[128 * 32];
  const int K = 512;
  int tid = threadIdx.x, lane = tid & 63, wid = tid >> 6;
  int wr = wid >> 1, wc = wid & 1;
  size_t row0 = (size_t)blockIdx.y * 128;
  int col0 = blockIdx.x * 128;
  int arow = lane >> 2, acol = (lane & 3) << 3;
  const unsigned short* Ag = A + (row0 + wid * 32 + arow) * K + acol;
  const unsigned short* B1g = Bt + ((size_t)(col0 + wid * 32 + arow)) * K + acol;
  const unsigned short* B2g = Bt + ((size_t)(col0 + 4096 + wid * 32 + arow)) * K + acol;
  short* Ald = Al + wid * 1024;
  short* B1d = B1l + wid * 1024;
  short* B2d = B2l + wid * 1024;
  f32x4 acc1[4][4] = {}, acc2[4][4] = {};
  int fr = lane & 15, fk = (lane >> 4) << 3;
  for (int k0 = 0; k0 < K; k0 += 32) {
    __syncthreads();
    gload16(Ag + k0, Ald);
    gload16(Ag + (size_t)16 * K + k0, Ald + 512);
    gload16(B1g + k0, B1d);
    gload16(B1g + (size_t)16 * K + k0, B1d + 512);
    gload16(B2g + k0, B2d);
    gload16(B2g + (size_t)16 * K + k0, B2d + 512);
    __syncthreads();
    bf16x8 af[4], b1f[4], b2f[4];
#pragma unroll
    for (int i = 0; i < 4; ++i) {
      af[i] = *(const bf16x8*)&Al[(wr * 64 + i * 16 + fr) * 32 + fk];
      b1f[i] = *(const bf16x8*)&B1l[(wc * 64 + i * 16 + fr) * 32 + fk];
      b2f[i] = *(const bf16x8*)&B2l[(wc * 64 + i * 16 + fr) * 32 + fk];
    }
#pragma unroll
    for (int i = 0; i < 4; ++i)
#pragma unroll
      for (int j = 0; j < 4; ++j) {
        acc1[i][j] = MFMA(af[i], b1f[j], acc1[i][j]);
        acc2[i][j] = MFMA(af[i], b2f[j], acc2[i][j]);
      }
  }
  int cr = (lane >> 4) << 2, cc = lane & 15;
#pragma unroll
  for (int j = 0; j < 4; ++j) {
    int col = col0 + wc * 64 + j * 16 + cc;
    float bb1 = bias[col], bb2 = bias[col + 4096];
#pragma unroll
    for (int i = 0; i < 4; ++i) {
#pragma unroll
      for (int r = 0; r < 4; ++r) {
        size_t row = row0 + wr * 64 + i * 16 + cr + r;
        float h1 = acc1[i][j][r] + bb1;
        float h2 = acc2[i][j][r] + bb2;
        float u = 0.7978845608028654f * (h1 + 0.044715f * h1 * h1 * h1);
        float e = __expf(2.f * u);
        float th = 1.f - 2.f / (e + 1.f);
        float gv = 0.5f * h1 * (1.f + th) * h2;
        out[row * 4096 + col] = f2bf(gv);
      }
    }
  }
}

// ---------------- RoPE in-place on qkv ----------------
// Q scale folds 1/sqrt(64) AND log2(e) (softmax uses exp2).
__global__ void k_rope(unsigned short* __restrict__ qkv) {
  int idx = blockIdx.x * 256 + threadIdx.x;  // [0, 8192*1024)
  int tok = idx >> 10;
  int rem = idx & 1023;
  int isk = rem >> 9;
  int h = (rem >> 5) & 15;
  int i = rem & 31;
  int m = tok & 2047;
  size_t base = (size_t)tok * 3072 + (size_t)isk * 1024 + h * 64 + i;
  float x1 = bf2f(qkv[base]);
  float x2 = bf2f(qkv[base + 32]);
  float ang = (float)m * __expf((float)i * -0.28782313662425575f);  // ln(10000)/32
  float sn, cs;
  __sincosf(ang, &sn, &cs);
  float sc = isk ? 1.f : 0.18033688011112042f;  // 0.125 * log2(e)
  qkv[base] = f2bf((x1 * cs - x2 * sn) * sc);
  qkv[base + 32] = f2bf((x2 * cs + x1 * sn) * sc);
}

// ---------------- flash attention (swapped-operand, in-register softmax) ----------------
// S^T = MFMA(K,Q); softmax in-lane; defer-max (T13); mask fast-path; deferred l-reduce;
// PV as O^T = MFMA(V^T, P) with cvt_pk + bpermute redistribution; setprio on MFMA (T5).
#define KIX(r, c) ((r) * 64 + ((c) ^ (((r) & 7) << 3)))

__global__ __launch_bounds__(256, 4) void k_attn(const unsigned short* __restrict__ qkv,
                                                 const unsigned short* __restrict__ vT,
                                                 const int* __restrict__ mask,
                                                 unsigned short* __restrict__ ctx) {
  __shared__ short Kl[64 * 64];
  __shared__ short Vl[64 * 64];
  __shared__ float mpen[64];
  __shared__ int mflag;
  int bh = blockIdx.y, b = bh >> 4, h = bh & 15;
  int q0 = blockIdx.x << 6;
  int tid = threadIdx.x, lane = tid & 63, wid = tid >> 6;
  int fr = lane & 15, fk = (lane >> 4) << 3;
  int g = lane >> 4, qi = lane & 15;
  const unsigned short* qbase =
      qkv + ((size_t)(b * 2048 + q0 + wid * 16 + fr)) * 3072 + h * 64;
  bf16x8 qa0 = *(const bf16x8*)(qbase + fk);
  bf16x8 qa1 = *(const bf16x8*)(qbase + 32 + fk);
  float m_r = -1e30f, l_r = 0.f;
  f32x4 cacc[4] = {};
  int srow = tid >> 2;
  int sc = (tid & 3) << 4;
  const unsigned short* kb =
      qkv + ((size_t)(b * 2048 + srow)) * 3072 + 1024 + h * 64 + sc;
  const unsigned short* vb = vT + ((size_t)bh * 64 + srow) * 2048 + sc;
  const int* mbase = mask + b * 2048;
  const f32x4 zero4 = {0.f, 0.f, 0.f, 0.f};
  // bpermute byte-addresses for P redistribution (hoisted)
  int addrA = (((g & 1) << 5) + qi) << 2;  // src lane (g&1)*32 + q
  int addrB = addrA + 64;                  // +16 lanes
  bool hi = ((g >> 1) & 1) != 0;
  // prefetch tile 0
  bf16x8 kn0 = *(const bf16x8*)kb;
  bf16x8 kn1 = *(const bf16x8*)(kb + 8);
  bf16x8 vn0 = *(const bf16x8*)vb;
  bf16x8 vn1 = *(const bf16x8*)(vb + 8);
  int mv = (tid < 64) ? mbase[tid] : 1;
  for (int k0 = 0; k0 < 2048; k0 += 64) {
    __syncthreads();  // prior tile's LDS reads drained
    *(bf16x8*)&Kl[KIX(srow, sc)] = kn0;
    *(bf16x8*)&Kl[KIX(srow, sc + 8)] = kn1;
    *(bf16x8*)&Vl[KIX(srow, sc)] = vn0;
    *(bf16x8*)&Vl[KIX(srow, sc + 8)] = vn1;
    if (wid == 0) {
      mpen[lane] = (mv == 0) ? -1e30f : 0.f;
      unsigned long long bal = __ballot(mv == 0);
      if (lane == 0) mflag = (bal != 0ull) ? 1 : 0;
    }
    if (k0 + 64 < 2048) {  // prefetch next tile (hidden under compute)
      kn0 = *(const bf16x8*)(kb + (size_t)(k0 + 64) * 3072);
      kn1 = *(const bf16x8*)(kb + (size_t)(k0 + 64) * 3072 + 8);
      vn0 = *(const bf16x8*)(vb + k0 + 64);
      vn1 = *(const bf16x8*)(vb + k0 + 64 + 8);
      mv = (tid < 64) ? mbase[k0 + 64 + tid] : 1;
    }
    __syncthreads();
    // S^T[k][q] = K · Q^T  (scale*log2e pre-folded into Q)
    f32x4 s[4];
    __builtin_amdgcn_s_setprio(1);
#pragma unroll
    for (int kt = 0; kt < 4; ++kt) {
      bf16x8 kf0 = *(const bf16x8*)&Kl[KIX(kt * 16 + fr, fk)];
      bf16x8 kf1 = *(const bf16x8*)&Kl[KIX(kt * 16 + fr, fk + 32)];
      s[kt] = MFMA(kf0, qa0, zero4);
      s[kt] = MFMA(kf1, qa1, s[kt]);
    }
    __builtin_amdgcn_s_setprio(0);
    // mask penalty: only when this tile has masked keys (wave-uniform)
    if (mflag) {
      const f32x4* mp4 = (const f32x4*)mpen;
#pragma unroll
      for (int kt = 0; kt < 4; ++kt) {
        f32x4 pen = mp4[kt * 4 + g];
#pragma unroll
        for (int r = 0; r < 4; ++r) s[kt][r] += pen[r];
      }
    }
    // tile max per q-column: max3 tree in-lane + 2 cross-lane steps
    float t0 = max3f(s[0][0], s[0][1], s[0][2]);
    float t1 = max3f(s[0][3], s[1][0], s[1][1]);
    float t2 = max3f(s[1][2], s[1][3], s[2][0]);
    float t3 = max3f(s[2][1], s[2][2], s[2][3]);
    float t4 = max3f(s[3][0], s[3][1], s[3][2]);
    float t5 = fmaxf(t0, s[3][3]);
    float pmax = max3f(max3f(t5, t1, t2), t3, t4);
    pmax = fmaxf(pmax, __shfl_xor(pmax, 16));
    pmax = fmaxf(pmax, __shfl_xor(pmax, 32));
    // defer-max: only rescale when tile max grew past threshold (log2 domain)
    if (!__all(pmax - m_r <= 8.f)) {
      float mn = fmaxf(m_r, pmax);
      float fac = exp2f(m_r - mn);
      m_r = mn;
      l_r *= fac;
#pragma unroll
      for (int dt = 0; dt < 4; ++dt)
#pragma unroll
        for (int r = 0; r < 4; ++r) cacc[dt][r] *= fac;
    }
    float su = 0.f;
#pragma unroll
    for (int kt = 0; kt < 4; ++kt)
#pragma unroll
      for (int r = 0; r < 4; ++r) {
        s[kt][r] = exp2f(s[kt][r] - m_r);
        su += s[kt][r];
      }
    l_r += su;  // per-lane partial; cross-lane reduced once at the end
    // pack P rows to bf16 pairs (RTNE via v_cvt_pk_bf16_f32)
    unsigned pk[4][2];
#pragma unroll
    for (int kt = 0; kt < 4; ++kt) {
      asm("v_cvt_pk_bf16_f32 %0, %1, %2" : "=v"(pk[kt][0]) : "v"(s[kt][0]), "v"(s[kt][1]));
      asm("v_cvt_pk_bf16_f32 %0, %1, %2" : "=v"(pk[kt][1]) : "v"(s[kt][2]), "v"(s[kt][3]));
    }
    // redistribute: D-layout (row k, col q) -> B-frag (row q, k=(lane>>4)*8+j)
    union { unsigned u[4]; bf16x8 v; } pb0, pb1;
    {
      unsigned a00 = __builtin_amdgcn_ds_bpermute(addrA, (int)pk[0][0]);
      unsigned a10 = __builtin_amdgcn_ds_bpermute(addrA, (int)pk[1][0]);
      unsigned a01 = __builtin_amdgcn_ds_bpermute(addrA, (int)pk[0][1]);
      unsigned a11 = __builtin_amdgcn_ds_bpermute(addrA, (int)pk[1][1]);
      unsigned b00 = __builtin_amdgcn_ds_bpermute(addrB, (int)pk[0][0]);
      unsigned b10 = __builtin_amdgcn_ds_bpermute(addrB, (int)pk[1][0]);
      unsigned b01 = __builtin_amdgcn_ds_bpermute(addrB, (int)pk[0][1]);
      unsigned b11 = __builtin_amdgcn_ds_bpermute(addrB, (int)pk[1][1]);
      pb0.u[0] = hi ? a10 : a00;
      pb0.u[1] = hi ? a11 : a01;
      pb0.u[2] = hi ? b10 : b00;
      pb0.u[3] = hi ? b11 : b01;
    }
    {
      unsigned a20 = __builtin_amdgcn_ds_bpermute(addrA, (int)pk[2][0]);
      unsigned a30 = __builtin_amdgcn_ds_bpermute(addrA, (int)pk[3][0]);
      unsigned a21 = __builtin_amdgcn_ds_bpermute(addrA, (int)pk[2][1]);
      unsigned a31 = __builtin_amdgcn_ds_bpermute(addrA, (int)pk[3][1]);
      unsigned b20 = __builtin_amdgcn_ds_bpermute(addrB, (int)pk[2][0]);
      unsigned b30 = __builtin_amdgcn_ds_bpermute(addrB, (int)pk[3][0]);
      unsigned b21 = __builtin_amdgcn_ds_bpermute(addrB, (int)pk[2][1]);
      unsigned b31 = __builtin_amdgcn_ds_bpermute(addrB, (int)pk[3][1]);
      pb1.u[0] = hi ? a30 : a20;
      pb1.u[1] = hi ? a31 : a21;
      pb1.u[2] = hi ? b30 : b20;
      pb1.u[3] = hi ? b31 : b21;
    }
    // O^T[d][q] += V^T · P   (col = q stays lane-local)
    __builtin_amdgcn_s_setprio(1);
#pragma unroll
    for (int dt = 0; dt < 4; ++dt) {
      bf16x8 vf0 = *(const bf16x8*)&Vl[KIX(dt * 16 + fr, fk)];
      bf16x8 vf1 = *(const bf16x8*)&Vl[KIX(dt * 16 + fr, fk + 32)];
      cacc[dt] = MFMA(vf0, pb0.v, cacc[dt]);
      cacc[dt] = MFMA(vf1, pb1.v, cacc[dt]);
    }
    __builtin_amdgcn_s_setprio(0);
  }
  // final cross-lane l reduction (linear; fac/m uniform across the 4 lanes per q)
  l_r += __shfl_xor(l_r, 16);
  l_r += __shfl_xor(l_r, 32);
  float invl = 1.f / l_r;
  unsigned short* obase =
      ctx + ((size_t)(b * 2048 + q0 + wid * 16 + qi)) * 1024 + h * 64 + (g << 2);
#pragma unroll
  for (int dt = 0; dt < 4; ++dt) {
    float v0 = cacc[dt][0] * invl, v1 = cacc[dt][1] * invl;
    float v2 = cacc[dt][2] * invl, v3 = cacc[dt][3] * invl;
    unsigned o0, o1;
    asm("v_cvt_pk_bf16_f32 %0, %1, %2" : "=v"(o0) : "v"(v0), "v"(v1));
    asm("v_cvt_pk_bf16_f32 %0, %1, %2" : "=v"(o1) : "v"(v2), "v"(v3));
    unsigned long long uu = ((unsigned long long)o1 << 32) | (unsigned long long)o0;
    *(unsigned long long*)(obase + dt * 16) = uu;
  }
}

// ---------------- launch ----------------
extern "C" void kernel_launch(void* const* d_in, const int* in_sizes, int n_in, void* d_out,
                              int out_size, void* d_ws, size_t ws_size, hipStream_t stream) {
  const float* x = (const float*)d_in[0];
  const int* amask = (const int*)d_in[1];
  const float* ln1w = (const float*)d_in[2];
  const float* ln1b = (const float*)d_in[3];
  const float* Uq = (const float*)d_in[4];
  const float* Vq = (const float*)d_in[5];
  const float* bq = (const float*)d_in[6];
  const float* Uk = (const float*)d_in[7];
  const float* Vk = (const float*)d_in[8];
  const float* bk = (const float*)d_in[9];
  const float* Uv = (const float*)d_in[10];
  const float* Vv = (const float*)d_in[11];
  const float* bv = (const float*)d_in[12];
  const float* Wo = (const float*)d_in[13];
  const float* bo = (const float*)d_in[14];
  const float* ln2w = (const float*)d_in[15];
  const float* ln2b = (const float*)d_in[16];
  const float* Uwi = (const float*)d_in[17];
  const float* Vwi = (const float*)d_in[18];
  const float* bwi = (const float*)d_in[19];
  const float* Uwo = (const float*)d_in[20];
  const float* Vwo = (const float*)d_in[21];
  const float* bwo = (const float*)d_in[22];

  char* ws = (char*)d_ws;
  size_t off = 0;
  auto alloc = [&](size_t bytes) {
    void* p = ws + off;
    off += (bytes + 255) & ~(size_t)255;
    return p;
  };
  // layout (~150 MB). g (64MB) aliases [qkv+ctx]; vT (16MB) aliases x1 (both dead then).
  unsigned short* xn = (unsigned short*)alloc((size_t)8192 * 1024 * 2);   // also xn2
  unsigned short* Wqkv = (unsigned short*)alloc((size_t)3072 * 1024 * 2);
  float* bqkv = (float*)alloc(3072 * 4);
  unsigned short* Wob = (unsigned short*)alloc((size_t)1024 * 1024 * 2);
  unsigned short* Uwit = (unsigned short*)alloc((size_t)512 * 1024 * 2);
  unsigned short* Vwit = (unsigned short*)alloc((size_t)8192 * 512 * 2);
  unsigned short* Uwot = (unsigned short*)alloc((size_t)512 * 4096 * 2);
  unsigned short* Vwot = (unsigned short*)alloc((size_t)1024 * 512 * 2);
  unsigned short* qkv = (unsigned short*)alloc((size_t)8192 * 3072 * 2);
  unsigned short* ctx = (unsigned short*)alloc((size_t)8192 * 1024 * 2);
  float* x1 = (float*)alloc((size_t)8192 * 1024 * 4);
  unsigned short* hr = (unsigned short*)alloc((size_t)8192 * 512 * 2);
  unsigned short* gr = (unsigned short*)alloc((size_t)8192 * 512 * 2);
  unsigned short* g = qkv;                 // alias: 64MB over qkv+ctx (dead by FFN)
  unsigned short* xn2 = xn;                // alias: xn dead after QKV gemm
  unsigned short* vT = (unsigned short*)x1;  // alias: x1 written only after attn
  if (off > ws_size) return;               // fail clean instead of faulting
  (void)in_sizes; (void)n_in; (void)out_size;

  dim3 tb(32, 8);
  // weight prep (runs every call; deterministic)
  k_build_wqkv<<<12288, 256, 0, stream>>>(Uq, Vq, Uk, Vk, Uv, Vv, Wqkv);
  k_concat_bias<<<12, 256, 0, stream>>>(bq, bk, bv, bqkv);
  k_f2bf<<<4096, 256, 0, stream>>>(Wo, Wob, 1024 * 1024);
  k_transpose_bf16<<<dim3(512 / 32, 1024 / 32), tb, 0, stream>>>(Uwi, Uwit, 1024, 512);
  k_transpose_bf16<<<dim3(8192 / 32, 512 / 32), tb, 0, stream>>>(Vwi, Vwit, 512, 8192);
  k_transpose_bf16<<<dim3(512 / 32, 4096 / 32), tb, 0, stream>>>(Uwo, Uwot, 4096, 512);
  k_transpose_bf16<<<dim3(1024 / 32, 512 / 32), tb, 0, stream>>>(Vwo, Vwot, 512, 1024);

  // block
  k_layernorm<<<8192, 256, 0, stream>>>(x, ln1w, ln1b, xn);
  k_gemm<1><<<dim3(24, 64), 256, 0, stream>>>(xn, Wqkv, bqkv, nullptr, qkv, 3072, 1024);
  k_rope<<<32768, 256, 0, stream>>>(qkv);
  k_vtrans<<<dim3(32, 64), 256, 0, stream>>>(qkv, vT);
  k_attn<<<dim3(32, 64), 256, 0, stream>>>(qkv, vT, amask, ctx);
  k_gemm<2><<<dim3(8, 64), 256, 0, stream>>>(ctx, Wob, bo, x, x1, 1024, 1024);
  k_layernorm<<<8192, 256, 0, stream>>>(x1, ln2w, ln2b, xn2);
  k_gemm<0><<<dim3(4, 64), 256, 0, stream>>>(xn2, Uwit, nullptr, nullptr, hr, 512, 1024);
  k_gemm_geglu<<<dim3(32, 64), 256, 0, stream>>>(hr, Vwit, bwi, g);
  k_gemm<0><<<dim3(4, 64), 256, 0, stream>>>(g, Uwot, nullptr, nullptr, gr, 512, 4096);
  k_gemm<2><<<dim3(8, 64), 256, 0, stream>>>(gr, Vwot, bwo, x1, d_out, 1024, 512);
}